// Round 1
// baseline (6583.510 us; speedup 1.0000x reference)
//
#include <hip/hip_runtime.h>
#include <math.h>

#define B_ 64
#define T_ 32
#define N_ 12
#define NS_ 132
#define KN_ 11
#define TEMP_ 1.375f   // K_NEIGH / sqrt(ATTN) = 11/8

__device__ __forceinline__ float sigm(float x) { return 1.f / (1.f + __expf(-x)); }
__device__ __forceinline__ float ftanh(float x) {
    float a = fabsf(x);
    float e = __expf(-2.f * a);
    float t = (1.f - e) / (1.f + e);
    return copysignf(t, x);
}

// ---------------------------------------------------------------------------
// prep: transpose/fuse weights once per call.
// Wt_t/Wt_s: [384][1024]  (k<128 -> Wih^T, else Whh^T), bs_* = bih+bhh
// Wt_n: [512][1024] (k<256 -> nr_Wih^T, else nr_Whh^T)
// WqT/WkT: [256][64], W_edgeT: [512][128]
// ---------------------------------------------------------------------------
__global__ __launch_bounds__(256) void prep_kernel(
    const float* __restrict__ te_Wih, const float* __restrict__ te_Whh,
    const float* __restrict__ te_bih, const float* __restrict__ te_bhh,
    const float* __restrict__ se_Wih, const float* __restrict__ se_Whh,
    const float* __restrict__ se_bih, const float* __restrict__ se_bhh,
    const float* __restrict__ nr_Wih, const float* __restrict__ nr_Whh,
    const float* __restrict__ nr_bih, const float* __restrict__ nr_bhh,
    const float* __restrict__ Wq, const float* __restrict__ Wk,
    const float* __restrict__ W_edge,
    float* __restrict__ Wt_t, float* __restrict__ Wt_s, float* __restrict__ Wt_n,
    float* __restrict__ bs_t, float* __restrict__ bs_s, float* __restrict__ bs_n,
    float* __restrict__ WqT, float* __restrict__ WkT, float* __restrict__ W_edgeT)
{
    int idx = blockIdx.x * 256 + threadIdx.x;   // grid covers 512*1024
    if (idx < 384 * 1024) {
        int k = idx >> 10, c = idx & 1023;
        Wt_t[idx] = (k < 128) ? te_Wih[c * 128 + k] : te_Whh[c * 256 + (k - 128)];
        Wt_s[idx] = (k < 128) ? se_Wih[c * 128 + k] : se_Whh[c * 256 + (k - 128)];
    }
    if (idx < 512 * 1024) {
        int k = idx >> 10, c = idx & 1023;
        Wt_n[idx] = (k < 256) ? nr_Wih[c * 256 + k] : nr_Whh[c * 256 + (k - 256)];
    }
    if (idx < 1024) {
        bs_t[idx] = te_bih[idx] + te_bhh[idx];
        bs_s[idx] = se_bih[idx] + se_bhh[idx];
        bs_n[idx] = nr_bih[idx] + nr_bhh[idx];
    }
    if (idx < 16384) {
        int k = idx >> 6, a = idx & 63;
        WqT[idx] = Wq[a * 256 + k];
        WkT[idx] = Wk[a * 256 + k];
    }
    if (idx < 65536) {
        int k = idx >> 7, c = idx & 127;
        W_edgeT[idx] = W_edge[c * 512 + k];
    }
}

// nin(b,t,n,c) = relu(nodes . W_node^T + b_node), all timesteps upfront
__global__ __launch_bounds__(256) void nin_kernel(
    const float* __restrict__ nodes, const float* __restrict__ W_node,
    const float* __restrict__ b_node, float* __restrict__ nin_all)
{
    int idx = blockIdx.x * 256 + threadIdx.x;
    if (idx >= B_ * T_ * N_ * 128) return;
    int c = idx & 127, r = idx >> 7;
    float v = nodes[r * 2] * W_node[c * 2] + nodes[r * 2 + 1] * W_node[c * 2 + 1] + b_node[c];
    nin_all[idx] = v > 0.f ? v : 0.f;
}

// ---------------------------------------------------------------------------
// Fused temporal+spatial LSTM step.
// grid: 528 spatial blocks (132 row-blocks x 4 j-tiles) + 48 temporal (12 x 4)
// Block tile: 64 rows x (16 j x 4 gates), K = 128(embed, computed inline) + 256(h)
// Each thread: acc[4r][4g][4j], fused LSTM-cell epilogue.
// ---------------------------------------------------------------------------
__global__ __launch_bounds__(256) void lstm_ts_kernel(
    int t,
    const float* __restrict__ et, const float* __restrict__ es,
    const float* __restrict__ W_te, const float* __restrict__ b_te,
    const float* __restrict__ W_se, const float* __restrict__ b_se,
    const float* __restrict__ Wt_t, const float* __restrict__ bs_t,
    const float* __restrict__ Wt_s, const float* __restrict__ bs_s,
    const float* __restrict__ h_t_prev, float* __restrict__ h_t_cur, float* __restrict__ c_t,
    const float* __restrict__ h_s_prev, float* __restrict__ h_s_cur, float* __restrict__ c_s)
{
    const int tid = threadIdx.x;
    const bool spatial = blockIdx.x < 528;
    const int bid = spatial ? blockIdx.x : blockIdx.x - 528;
    const int nrb = spatial ? 132 : 12;
    const int rb = bid % nrb, jt = bid / nrb;
    const int row0 = rb * 64;
    const int ns = spatial ? NS_ : N_;
    const float* E = spatial ? es : et;
    const float* Wemb = spatial ? W_se : W_te;
    const float* bemb = spatial ? b_se : b_te;
    const float* Wt   = spatial ? Wt_s : Wt_t;
    const float* bsum = spatial ? bs_s : bs_t;
    const float* Hprev = spatial ? h_s_prev : h_t_prev;
    float* Hcur = spatial ? h_s_cur : h_t_cur;
    float* C    = spatial ? c_s : c_t;

    __shared__ float Els[64][2];
    __shared__ float Xs[16][68];   // [k][row], padded: conflict-free transpose writes
    __shared__ float Ws[16][256];  // [k][g*64 + j]

    if (tid < 128) {
        int r = tid >> 1, comp = tid & 1;
        int row = row0 + r;
        int b = row / ns, s = row % ns;
        Els[r][comp] = E[(((size_t)b * T_ + t) * ns + s) * 2 + comp];
    }
    __syncthreads();

    const int tx = tid & 15, ty = tid >> 4;
    float acc[4][4][4]; // [r][g][j]
    #pragma unroll
    for (int g = 0; g < 4; ++g)
        #pragma unroll
        for (int j = 0; j < 4; ++j) {
            float bv = bsum[g * 256 + jt * 64 + tx * 4 + j];
            #pragma unroll
            for (int r = 0; r < 4; ++r) acc[r][g][j] = bv;
        }

    for (int kc = 0; kc < 24; ++kc) {
        { // stage X[k][r]: embed chunks (kc<8) computed inline, else h_prev
            int r = tid >> 2, kq = tid & 3;
            int kglob = kc * 16 + kq * 4;
            float v[4];
            if (kc < 8) {
                float e0 = Els[r][0], e1 = Els[r][1];
                #pragma unroll
                for (int i = 0; i < 4; ++i) {
                    int k = kglob + i;
                    float val = e0 * Wemb[k * 2] + e1 * Wemb[k * 2 + 1] + bemb[k];
                    v[i] = val > 0.f ? val : 0.f;
                }
            } else {
                const float4 h4 = *(const float4*)&Hprev[(size_t)(row0 + r) * 256 + (kglob - 128)];
                v[0] = h4.x; v[1] = h4.y; v[2] = h4.z; v[3] = h4.w;
            }
            #pragma unroll
            for (int i = 0; i < 4; ++i) Xs[kq * 4 + i][r] = v[i];
        }
        { // stage W: 4 float4 per thread, coalesced
            #pragma unroll
            for (int q = 0; q < 4; ++q) {
                int f = q * 256 + tid;
                int k = f >> 6, c4 = f & 63;
                int g = c4 >> 4, j = (c4 & 15) * 4;
                const float4 w4 = *(const float4*)&Wt[(size_t)(kc * 16 + k) * 1024 + g * 256 + jt * 64 + j];
                *(float4*)&Ws[k][c4 * 4] = w4;
            }
        }
        __syncthreads();
        #pragma unroll
        for (int k = 0; k < 16; ++k) {
            float4 xv = *(const float4*)&Xs[k][ty * 4];
            float xr[4] = {xv.x, xv.y, xv.z, xv.w};
            #pragma unroll
            for (int g = 0; g < 4; ++g) {
                float4 wv = *(const float4*)&Ws[k][g * 64 + tx * 4];
                float wj[4] = {wv.x, wv.y, wv.z, wv.w};
                #pragma unroll
                for (int r = 0; r < 4; ++r)
                    #pragma unroll
                    for (int j = 0; j < 4; ++j)
                        acc[r][g][j] = fmaf(xr[r], wj[j], acc[r][g][j]);
            }
        }
        __syncthreads();
    }

    // fused LSTM cell epilogue (i,f,g,o all live per thread)
    #pragma unroll
    for (int r = 0; r < 4; ++r) {
        int row = row0 + ty * 4 + r;
        int col0 = jt * 64 + tx * 4;
        const float4 cold = *(const float4*)&C[(size_t)row * 256 + col0];
        float cd[4] = {cold.x, cold.y, cold.z, cold.w};
        float hv[4], cv[4];
        #pragma unroll
        for (int j = 0; j < 4; ++j) {
            float gi = acc[r][0][j], gf = acc[r][1][j], gg = acc[r][2][j], go = acc[r][3][j];
            float c2 = sigm(gf) * cd[j] + sigm(gi) * ftanh(gg);
            float h2 = sigm(go) * ftanh(c2);
            cv[j] = c2; hv[j] = h2;
        }
        *(float4*)&Hcur[(size_t)row * 256 + col0] = make_float4(hv[0], hv[1], hv[2], hv[3]);
        *(float4*)&C[(size_t)row * 256 + col0]    = make_float4(cv[0], cv[1], cv[2], cv[3]);
    }
}

// ---------------------------------------------------------------------------
// Attention + edge-input per (b,n): q, k-projection via qk = Wk^T q trick,
// softmax over 11 neighbors, h_attn, then ein = relu(W_edge [h_temp|h_attn]).
// ---------------------------------------------------------------------------
__global__ __launch_bounds__(256) void attn_kernel(
    const float* __restrict__ h_t_cur, const float* __restrict__ h_s_cur,
    const float* __restrict__ WqT, const float* __restrict__ bq,
    const float* __restrict__ WkT, const float* __restrict__ bk,
    const float* __restrict__ W_edgeT, const float* __restrict__ b_edge,
    float* __restrict__ ein_buf)
{
    const int tid = threadIdx.x;
    const int b = blockIdx.x / N_, n = blockIdx.x % N_;
    const int row = blockIdx.x;

    __shared__ float ht[256];
    __shared__ float hpn[11][256];
    __shared__ float qp[4][64];
    __shared__ float qv[64];
    __shared__ float qk[256];
    __shared__ float scp[11][16];
    __shared__ float sc[11];
    __shared__ float hattn[256];
    __shared__ float ep[2][128];

    ht[tid] = h_t_cur[(size_t)row * 256 + tid];
    const int base = b * NS_ + n * KN_;
    #pragma unroll
    for (int kk = 0; kk < 11; ++kk)
        hpn[kk][tid] = h_s_cur[(size_t)(base + kk) * 256 + tid];
    __syncthreads();

    { // q = Wq h_temp + bq (split K over 4 partials)
        int a = tid & 63, p = tid >> 6;
        float s = 0.f;
        for (int k = p * 64; k < p * 64 + 64; ++k)
            s = fmaf(ht[k], WqT[k * 64 + a], s);
        qp[p][a] = s;
    }
    __syncthreads();
    if (tid < 64) qv[tid] = bq[tid] + qp[0][tid] + qp[1][tid] + qp[2][tid] + qp[3][tid];
    __syncthreads();
    { // qk = Wk^T q  (then scores[kk] = qk . hpn[kk] + q.bk)
        float s = 0.f;
        for (int a = 0; a < 64; ++a) s = fmaf(qv[a], WkT[tid * 64 + a], s);
        qk[tid] = s;
    }
    float qb = 0.f;
    for (int a = 0; a < 64; ++a) qb = fmaf(qv[a], bk[a], qb);
    __syncthreads();
    if (tid < 176) {
        int kk = tid >> 4, p = tid & 15;
        float s = 0.f;
        for (int k = p * 16; k < p * 16 + 16; ++k)
            s = fmaf(qk[k], hpn[kk][k], s);
        scp[kk][p] = s;
    }
    __syncthreads();
    if (tid < 11) {
        float s = 0.f;
        #pragma unroll
        for (int p = 0; p < 16; ++p) s += scp[tid][p];
        sc[tid] = (s + qb) * TEMP_;
    }
    __syncthreads();

    float w[11];
    {
        float m = sc[0];
        #pragma unroll
        for (int kk = 1; kk < 11; ++kk) m = fmaxf(m, sc[kk]);
        float ssum = 0.f;
        #pragma unroll
        for (int kk = 0; kk < 11; ++kk) { w[kk] = __expf(sc[kk] - m); ssum += w[kk]; }
        float inv = 1.f / ssum;
        #pragma unroll
        for (int kk = 0; kk < 11; ++kk) w[kk] *= inv;
    }
    {
        float s = 0.f;
        #pragma unroll
        for (int kk = 0; kk < 11; ++kk) s = fmaf(w[kk], hpn[kk][tid], s);
        hattn[tid] = s;
    }
    __syncthreads();
    { // ein = relu(W_edge [ht|hattn] + b_edge)
        int c = tid & 127, p = tid >> 7;
        float s = 0.f;
        for (int k = p * 256; k < p * 256 + 256; ++k) {
            float x = (k < 256) ? ht[k] : hattn[k - 256];
            s = fmaf(x, W_edgeT[(size_t)k * 128 + c], s);
        }
        ep[p][c] = s;
    }
    __syncthreads();
    if (tid < 128) {
        float v = ep[0][tid] + ep[1][tid] + b_edge[tid];
        ein_buf[(size_t)row * 128 + tid] = v > 0.f ? v : 0.f;
    }
}

// ---------------------------------------------------------------------------
// Node LSTM step. 768 rows x 1024 gates, K=512 = [nin(128)|ein(128)|h_node(256)]
// grid: 24 row-blocks (32 rows) x 4 j-tiles = 96 blocks.
// ---------------------------------------------------------------------------
__global__ __launch_bounds__(256) void node_lstm_kernel(
    int t,
    const float* __restrict__ nin_all, const float* __restrict__ ein_buf,
    const float* __restrict__ Wt_n, const float* __restrict__ bs_n,
    const float* __restrict__ h_n_prev, float* __restrict__ h_n_cur,
    float* __restrict__ c_n, float* __restrict__ hist)
{
    const int tid = threadIdx.x;
    const int rb = blockIdx.x % 24, jt = blockIdx.x / 24;
    const int row0 = rb * 32;

    __shared__ float Xs[16][36];
    __shared__ float Ws[16][256];

    const int tx = tid & 15, ty = tid >> 4;
    float acc[2][4][4];
    #pragma unroll
    for (int g = 0; g < 4; ++g)
        #pragma unroll
        for (int j = 0; j < 4; ++j) {
            float bv = bs_n[g * 256 + jt * 64 + tx * 4 + j];
            acc[0][g][j] = bv; acc[1][g][j] = bv;
        }

    for (int kc = 0; kc < 32; ++kc) {
        if (tid < 128) {
            int r = tid >> 2, kq = tid & 3;
            int kglob = kc * 16 + kq * 4;
            int row = row0 + r;
            float4 t4;
            if (kc < 8) {
                int b = row / 12, n = row % 12;
                t4 = *(const float4*)&nin_all[((size_t)(b * T_ + t) * 12 + n) * 128 + kglob];
            } else if (kc < 16) {
                t4 = *(const float4*)&ein_buf[(size_t)row * 128 + (kglob - 128)];
            } else {
                t4 = *(const float4*)&h_n_prev[(size_t)row * 256 + (kglob - 256)];
            }
            float v[4] = {t4.x, t4.y, t4.z, t4.w};
            #pragma unroll
            for (int i = 0; i < 4; ++i) Xs[kq * 4 + i][r] = v[i];
        }
        {
            #pragma unroll
            for (int q = 0; q < 4; ++q) {
                int f = q * 256 + tid;
                int k = f >> 6, c4 = f & 63;
                int g = c4 >> 4, j = (c4 & 15) * 4;
                const float4 w4 = *(const float4*)&Wt_n[(size_t)(kc * 16 + k) * 1024 + g * 256 + jt * 64 + j];
                *(float4*)&Ws[k][c4 * 4] = w4;
            }
        }
        __syncthreads();
        #pragma unroll
        for (int k = 0; k < 16; ++k) {
            float2 xv = *(const float2*)&Xs[k][ty * 2];
            float xr[2] = {xv.x, xv.y};
            #pragma unroll
            for (int g = 0; g < 4; ++g) {
                float4 wv = *(const float4*)&Ws[k][g * 64 + tx * 4];
                float wj[4] = {wv.x, wv.y, wv.z, wv.w};
                #pragma unroll
                for (int r = 0; r < 2; ++r)
                    #pragma unroll
                    for (int j = 0; j < 4; ++j)
                        acc[r][g][j] = fmaf(xr[r], wj[j], acc[r][g][j]);
            }
        }
        __syncthreads();
    }

    #pragma unroll
    for (int r = 0; r < 2; ++r) {
        int row = row0 + ty * 2 + r;
        int col0 = jt * 64 + tx * 4;
        const float4 cold = *(const float4*)&c_n[(size_t)row * 256 + col0];
        float cd[4] = {cold.x, cold.y, cold.z, cold.w};
        float hv[4], cv[4];
        #pragma unroll
        for (int j = 0; j < 4; ++j) {
            float gi = acc[r][0][j], gf = acc[r][1][j], gg = acc[r][2][j], go = acc[r][3][j];
            float c2 = sigm(gf) * cd[j] + sigm(gi) * ftanh(gg);
            float h2 = sigm(go) * ftanh(c2);
            cv[j] = c2; hv[j] = h2;
        }
        float4 h4 = make_float4(hv[0], hv[1], hv[2], hv[3]);
        *(float4*)&h_n_cur[(size_t)row * 256 + col0] = h4;
        *(float4*)&c_n[(size_t)row * 256 + col0] = make_float4(cv[0], cv[1], cv[2], cv[3]);
        *(float4*)&hist[((size_t)t * 768 + row) * 256 + col0] = h4;
    }
}

// final out projection: out[b,t,n,q] = h_node_hist . W_out^T + b_out
__global__ __launch_bounds__(256) void out_kernel(
    const float* __restrict__ hist, const float* __restrict__ W_out,
    const float* __restrict__ b_out, float* __restrict__ out)
{
    const int lane = threadIdx.x & 63;
    const int grp = threadIdx.x >> 6;
    for (int ridx = blockIdx.x * 4 + grp; ridx < 32 * 768; ridx += gridDim.x * 4) {
        int t = ridx / 768, row = ridx % 768;
        int b = row / 12, n = row % 12;
        const float* h = &hist[(size_t)ridx * 256];
        float hv[4];
        #pragma unroll
        for (int i = 0; i < 4; ++i) hv[i] = h[i * 64 + lane];
        #pragma unroll
        for (int q = 0; q < 5; ++q) {
            float s = 0.f;
            #pragma unroll
            for (int i = 0; i < 4; ++i) s = fmaf(hv[i], W_out[q * 256 + i * 64 + lane], s);
            #pragma unroll
            for (int off = 32; off > 0; off >>= 1) s += __shfl_down(s, off, 64);
            if (lane == 0)
                out[(((size_t)b * T_ + t) * N_ + n) * 5 + q] = s + b_out[q];
        }
    }
}

extern "C" void kernel_launch(void* const* d_in, const int* in_sizes, int n_in,
                              void* d_out, int out_size, void* d_ws, size_t ws_size,
                              hipStream_t stream)
{
    const float* nodes = (const float*)d_in[0];
    const float* et    = (const float*)d_in[1];
    const float* es    = (const float*)d_in[2];
    const float* W_te = (const float*)d_in[3];  const float* b_te = (const float*)d_in[4];
    const float* te_Wih = (const float*)d_in[5]; const float* te_Whh = (const float*)d_in[6];
    const float* te_bih = (const float*)d_in[7]; const float* te_bhh = (const float*)d_in[8];
    const float* W_se = (const float*)d_in[9];  const float* b_se = (const float*)d_in[10];
    const float* se_Wih = (const float*)d_in[11]; const float* se_Whh = (const float*)d_in[12];
    const float* se_bih = (const float*)d_in[13]; const float* se_bhh = (const float*)d_in[14];
    const float* Wq = (const float*)d_in[15]; const float* bq = (const float*)d_in[16];
    const float* Wk = (const float*)d_in[17]; const float* bk = (const float*)d_in[18];
    const float* W_node = (const float*)d_in[19]; const float* b_node = (const float*)d_in[20];
    const float* W_edge = (const float*)d_in[21]; const float* b_edge = (const float*)d_in[22];
    const float* nr_Wih = (const float*)d_in[23]; const float* nr_Whh = (const float*)d_in[24];
    const float* nr_bih = (const float*)d_in[25]; const float* nr_bhh = (const float*)d_in[26];
    const float* W_out = (const float*)d_in[27]; const float* b_out = (const float*)d_in[28];

    float* ws = (float*)d_ws;
    size_t off = 0;
    auto alloc = [&](size_t n) { float* p = ws + off; off += n; return p; };

    float* h_t[2]; h_t[0] = alloc(768 * 256); h_t[1] = alloc(768 * 256);
    float* c_t = alloc(768 * 256);
    float* h_s[2]; h_s[0] = alloc(8448 * 256); h_s[1] = alloc(8448 * 256);
    float* c_s = alloc(8448 * 256);
    float* h_n[2]; h_n[0] = alloc(768 * 256); h_n[1] = alloc(768 * 256);
    float* c_n = alloc(768 * 256);
    size_t state_floats = off;
    float* nin_all = alloc((size_t)B_ * T_ * N_ * 128);
    float* hist    = alloc((size_t)T_ * 768 * 256);
    float* ein_buf = alloc(768 * 128);
    float* Wt_t = alloc(384 * 1024);
    float* Wt_s = alloc(384 * 1024);
    float* Wt_n = alloc(512 * 1024);
    float* bs_t = alloc(1024); float* bs_s = alloc(1024); float* bs_n = alloc(1024);
    float* WqT = alloc(256 * 64); float* WkT = alloc(256 * 64);
    float* W_edgeT = alloc(512 * 128);

    hipMemsetAsync(ws, 0, state_floats * sizeof(float), stream);

    prep_kernel<<<2048, 256, 0, stream>>>(
        te_Wih, te_Whh, te_bih, te_bhh, se_Wih, se_Whh, se_bih, se_bhh,
        nr_Wih, nr_Whh, nr_bih, nr_bhh, Wq, Wk, W_edge,
        Wt_t, Wt_s, Wt_n, bs_t, bs_s, bs_n, WqT, WkT, W_edgeT);

    nin_kernel<<<(B_ * T_ * N_ * 128 + 255) / 256, 256, 0, stream>>>(nodes, W_node, b_node, nin_all);

    for (int t = 0; t < T_; ++t) {
        int pp = t & 1, cc = pp ^ 1;
        lstm_ts_kernel<<<576, 256, 0, stream>>>(
            t, et, es, W_te, b_te, W_se, b_se, Wt_t, bs_t, Wt_s, bs_s,
            h_t[pp], h_t[cc], c_t, h_s[pp], h_s[cc], c_s);
        attn_kernel<<<768, 256, 0, stream>>>(
            h_t[cc], h_s[cc], WqT, bq, WkT, bk, W_edgeT, b_edge, ein_buf);
        node_lstm_kernel<<<96, 256, 0, stream>>>(
            t, nin_all, ein_buf, Wt_n, bs_n, h_n[pp], h_n[cc], c_n, hist);
    }

    out_kernel<<<1536, 256, 0, stream>>>(hist, W_out, b_out, (float*)d_out);
}

// Round 2
// 1899.932 us; speedup vs baseline: 3.4651x; 3.4651x over previous
//
#include <hip/hip_runtime.h>
#include <math.h>

#define B_ 64
#define T_ 32
#define N_ 12
#define NS_ 132
#define KN_ 11
#define TEMP_ 1.375f   // K_NEIGH / sqrt(ATTN) = 11/8

typedef unsigned short u16;
typedef __attribute__((ext_vector_type(8))) short bf16x8;
typedef __attribute__((ext_vector_type(4))) float f32x4;

__device__ __forceinline__ float sigm(float x) { return 1.f / (1.f + __expf(-x)); }
__device__ __forceinline__ float ftanh(float x) {
    float a = fabsf(x);
    float e = __expf(-2.f * a);
    float t = (1.f - e) / (1.f + e);
    return copysignf(t, x);
}
__device__ __forceinline__ u16 f2bf(float x) {
    union { float f; unsigned u; } v; v.f = x;
    unsigned r = v.u + 0x7fffu + ((v.u >> 16) & 1u);
    return (u16)(r >> 16);
}
__device__ __forceinline__ float bf2f(u16 h) {
    union { unsigned u; float f; } v; v.u = ((unsigned)h) << 16; return v.f;
}
// weight-column reorder: J = cellhi*64 + gate*16 + celllo  ->  orig col = gate*256 + cell
__device__ __forceinline__ int origcol(int j) {
    return ((j >> 4) & 3) * 256 + ((j >> 6) << 4) + (j & 15);
}

// ---------------------------------------------------------------------------
// prep: bf16 transposed+reordered weights, fused biases, attn weight transposes
// WtT_t/WtT_s: [1024][384] bf16 (col-major weights, gate-interleaved rows)
// WtT_n: [1024][512] bf16.  bs_*: reordered bih+bhh (f32).
// ---------------------------------------------------------------------------
__global__ __launch_bounds__(256) void prep_kernel(
    const float* __restrict__ te_Wih, const float* __restrict__ te_Whh,
    const float* __restrict__ te_bih, const float* __restrict__ te_bhh,
    const float* __restrict__ se_Wih, const float* __restrict__ se_Whh,
    const float* __restrict__ se_bih, const float* __restrict__ se_bhh,
    const float* __restrict__ nr_Wih, const float* __restrict__ nr_Whh,
    const float* __restrict__ nr_bih, const float* __restrict__ nr_bhh,
    const float* __restrict__ Wq, const float* __restrict__ Wk,
    const float* __restrict__ W_edge,
    u16* __restrict__ WtT_t, u16* __restrict__ WtT_s, u16* __restrict__ WtT_n,
    float* __restrict__ bs_t, float* __restrict__ bs_s, float* __restrict__ bs_n,
    float* __restrict__ WqT, float* __restrict__ WkT, float* __restrict__ W_edgeT)
{
    int idx = blockIdx.x * 256 + threadIdx.x;   // grid covers 1024*512
    if (idx < 1024 * 384) {
        int j = idx / 384, k = idx - j * 384;
        int c = origcol(j);
        float vt = (k < 128) ? te_Wih[c * 128 + k] : te_Whh[c * 256 + (k - 128)];
        float vs = (k < 128) ? se_Wih[c * 128 + k] : se_Whh[c * 256 + (k - 128)];
        WtT_t[idx] = f2bf(vt);
        WtT_s[idx] = f2bf(vs);
    }
    if (idx < 1024 * 512) {
        int j = idx >> 9, k = idx & 511;
        int c = origcol(j);
        WtT_n[idx] = f2bf((k < 256) ? nr_Wih[c * 256 + k] : nr_Whh[c * 256 + (k - 256)]);
    }
    if (idx < 1024) {
        int c = origcol(idx);
        bs_t[idx] = te_bih[c] + te_bhh[c];
        bs_s[idx] = se_bih[c] + se_bhh[c];
        bs_n[idx] = nr_bih[c] + nr_bhh[c];
    }
    if (idx < 16384) {
        int k = idx >> 6, a = idx & 63;
        WqT[idx] = Wq[a * 256 + k];
        WkT[idx] = Wk[a * 256 + k];
    }
    if (idx < 65536) {
        int k = idx >> 7, c = idx & 127;
        W_edgeT[idx] = W_edge[c * 512 + k];
    }
}

// te_all[t][row][128] bf16 and nin_all[t][row][128] bf16, row = b*12+n
__global__ __launch_bounds__(256) void emb_tn_kernel(
    const float* __restrict__ et, const float* __restrict__ nodes,
    const float* __restrict__ W_te, const float* __restrict__ b_te,
    const float* __restrict__ W_node, const float* __restrict__ b_node,
    u16* __restrict__ te_all, u16* __restrict__ nin_all)
{
    int idx = blockIdx.x * 256 + threadIdx.x;   // exactly 32*768*128
    int k = idx & 127;
    int rowT = idx >> 7;
    int t = rowT / 768, row = rowT - t * 768;
    int b = row / 12, n = row - b * 12;
    size_t src = (((size_t)b * T_ + t) * N_ + n) * 2;
    float v = et[src] * W_te[k * 2] + et[src + 1] * W_te[k * 2 + 1] + b_te[k];
    te_all[idx] = f2bf(fmaxf(v, 0.f));
    float w = nodes[src] * W_node[k * 2] + nodes[src + 1] * W_node[k * 2 + 1] + b_node[k];
    nin_all[idx] = f2bf(fmaxf(w, 0.f));
}

// se embed for t in [t0, t0+count): out[(t-t0)*8448 + row][128] bf16
__global__ __launch_bounds__(256) void emb_se_kernel(
    int t0, const float* __restrict__ es,
    const float* __restrict__ W_se, const float* __restrict__ b_se,
    u16* __restrict__ out)
{
    int idx = blockIdx.x * 256 + threadIdx.x;   // count*8448*128, exact
    int k = idx & 127;
    int rowT = idx >> 7;
    int trel = rowT / 8448, row = rowT - trel * 8448;
    int b = row / NS_, s = row - b * NS_;
    size_t src = (((size_t)b * T_ + (t0 + trel)) * NS_ + s) * 2;
    float v = es[src] * W_se[k * 2] + es[src + 1] * W_se[k * 2 + 1] + b_se[k];
    out[idx] = f2bf(fmaxf(v, 0.f));
}

// ---------------------------------------------------------------------------
// Fused temporal+spatial LSTM step, MFMA bf16.
// grid: 528 spatial (66 rb x 8 jt) + 48 temporal (6 rb x 8 jt), 256 thr.
// Block tile 128 rows x 128 gate-cols, 4 waves 2x2, wave tile 64x64.
// K = 384 = embed(128, precomputed bf16) + h_prev(256, bf16). BK=32, 12 iters.
// ---------------------------------------------------------------------------
__global__ __launch_bounds__(256) void lstm_ts_mfma(
    int t,
    const u16* __restrict__ se_step,   // [8448][128] for this step
    const u16* __restrict__ te_all,    // [T][768][128]
    const u16* __restrict__ WtT_t, const float* __restrict__ bs_t,
    const u16* __restrict__ WtT_s, const float* __restrict__ bs_s,
    const u16* __restrict__ h_t_prev, u16* __restrict__ h_t_cur, float* __restrict__ c_t,
    const u16* __restrict__ h_s_prev, u16* __restrict__ h_s_cur, float* __restrict__ c_s)
{
    const int tid = threadIdx.x;
    const bool spatial = blockIdx.x < 528;
    const int bid = spatial ? blockIdx.x : blockIdx.x - 528;
    const int rb = bid >> 3, jt = bid & 7;
    const int row0 = rb * 128;
    const u16* Emb = spatial ? se_step : te_all + (size_t)t * 768 * 128;
    const u16* WtT = spatial ? WtT_s : WtT_t;
    const float* bs = spatial ? bs_s : bs_t;
    const u16* Hp = spatial ? h_s_prev : h_t_prev;
    u16* Hc = spatial ? h_s_cur : h_t_cur;
    float* C = spatial ? c_s : c_t;

    __shared__ u16 A_lds[128 * 72];
    __shared__ u16 B_lds[128 * 72];

    const int l = tid & 63, wid = tid >> 6;
    const int wm = wid >> 1, wn = wid & 1;
    const int l15 = l & 15, lk = (l >> 4) * 8;

    f32x4 acc[4][4];   // [mf][gate]
    #pragma unroll
    for (int g = 0; g < 4; ++g) {
        float bv = bs[jt * 128 + wn * 64 + g * 16 + l15];
        #pragma unroll
        for (int mf = 0; mf < 4; ++mf) acc[mf][g] = (f32x4){bv, bv, bv, bv};
    }

    const int srow = tid >> 1, sseg = tid & 1;   // staging: 2 threads per 64B row
    for (int kc = 0; kc < 12; ++kc) {
        const int k0 = kc * 32;
        const u16* asrc = (kc < 4)
            ? Emb + (size_t)(row0 + srow) * 128 + k0 + sseg * 16
            : Hp  + (size_t)(row0 + srow) * 256 + (k0 - 128) + sseg * 16;
        float4 a0 = *(const float4*)asrc;
        float4 a1 = *(const float4*)(asrc + 8);
        const u16* bsrc = WtT + (size_t)(jt * 128 + srow) * 384 + k0 + sseg * 16;
        float4 b0 = *(const float4*)bsrc;
        float4 b1 = *(const float4*)(bsrc + 8);
        __syncthreads();
        *(float4*)&A_lds[srow * 72 + sseg * 16]     = a0;
        *(float4*)&A_lds[srow * 72 + sseg * 16 + 8] = a1;
        *(float4*)&B_lds[srow * 72 + sseg * 16]     = b0;
        *(float4*)&B_lds[srow * 72 + sseg * 16 + 8] = b1;
        __syncthreads();
        bf16x8 afr[4], bfr[4];
        #pragma unroll
        for (int mf = 0; mf < 4; ++mf)
            afr[mf] = *(const bf16x8*)&A_lds[(wm * 64 + mf * 16 + l15) * 72 + lk];
        #pragma unroll
        for (int g = 0; g < 4; ++g)
            bfr[g] = *(const bf16x8*)&B_lds[(wn * 64 + g * 16 + l15) * 72 + lk];
        #pragma unroll
        for (int mf = 0; mf < 4; ++mf)
            #pragma unroll
            for (int g = 0; g < 4; ++g)
                acc[mf][g] = __builtin_amdgcn_mfma_f32_16x16x32_bf16(afr[mf], bfr[g], acc[mf][g], 0, 0, 0);
    }

    // fused LSTM epilogue: thread holds all 4 gates of cell=(jt*2+wn)*16+l15
    const int cell = (jt * 2 + wn) * 16 + l15;
    const int rofs = ((l >> 4) << 2);
    #pragma unroll
    for (int mf = 0; mf < 4; ++mf) {
        int rowb = row0 + wm * 64 + mf * 16 + rofs;
        #pragma unroll
        for (int r = 0; r < 4; ++r) {
            size_t off = (size_t)(rowb + r) * 256 + cell;
            float gi = acc[mf][0][r], gf = acc[mf][1][r], gg = acc[mf][2][r], go = acc[mf][3][r];
            float c2 = sigm(gf) * C[off] + sigm(gi) * ftanh(gg);
            float h2 = sigm(go) * ftanh(c2);
            C[off] = c2;
            Hc[off] = f2bf(h2);
        }
    }
}

// ---------------------------------------------------------------------------
// Attention + edge-input per (b,n) — fp32 vector math, bf16 h in/out.
// ---------------------------------------------------------------------------
__global__ __launch_bounds__(256) void attn_kernel(
    const u16* __restrict__ h_t_cur, const u16* __restrict__ h_s_cur,
    const float* __restrict__ WqT, const float* __restrict__ bq,
    const float* __restrict__ WkT, const float* __restrict__ bk,
    const float* __restrict__ W_edgeT, const float* __restrict__ b_edge,
    u16* __restrict__ ein_buf)
{
    const int tid = threadIdx.x;
    const int b = blockIdx.x / N_, n = blockIdx.x % N_;
    const int row = blockIdx.x;

    __shared__ float ht[256];
    __shared__ float hpn[11][256];
    __shared__ float qp[4][64];
    __shared__ float qv[64];
    __shared__ float qk[256];
    __shared__ float scp[11][16];
    __shared__ float sc[11];
    __shared__ float hattn[256];
    __shared__ float ep[2][128];

    ht[tid] = bf2f(h_t_cur[(size_t)row * 256 + tid]);
    const int base = b * NS_ + n * KN_;
    #pragma unroll
    for (int kk = 0; kk < 11; ++kk)
        hpn[kk][tid] = bf2f(h_s_cur[(size_t)(base + kk) * 256 + tid]);
    __syncthreads();

    {
        int a = tid & 63, p = tid >> 6;
        float s = 0.f;
        for (int k = p * 64; k < p * 64 + 64; ++k)
            s = fmaf(ht[k], WqT[k * 64 + a], s);
        qp[p][a] = s;
    }
    __syncthreads();
    if (tid < 64) qv[tid] = bq[tid] + qp[0][tid] + qp[1][tid] + qp[2][tid] + qp[3][tid];
    __syncthreads();
    {
        float s = 0.f;
        for (int a = 0; a < 64; ++a) s = fmaf(qv[a], WkT[tid * 64 + a], s);
        qk[tid] = s;
    }
    float qb = 0.f;
    for (int a = 0; a < 64; ++a) qb = fmaf(qv[a], bk[a], qb);
    __syncthreads();
    if (tid < 176) {
        int kk = tid >> 4, p = tid & 15;
        float s = 0.f;
        for (int k = p * 16; k < p * 16 + 16; ++k)
            s = fmaf(qk[k], hpn[kk][k], s);
        scp[kk][p] = s;
    }
    __syncthreads();
    if (tid < 11) {
        float s = 0.f;
        #pragma unroll
        for (int p = 0; p < 16; ++p) s += scp[tid][p];
        sc[tid] = (s + qb) * TEMP_;
    }
    __syncthreads();

    float w[11];
    {
        float m = sc[0];
        #pragma unroll
        for (int kk = 1; kk < 11; ++kk) m = fmaxf(m, sc[kk]);
        float ssum = 0.f;
        #pragma unroll
        for (int kk = 0; kk < 11; ++kk) { w[kk] = __expf(sc[kk] - m); ssum += w[kk]; }
        float inv = 1.f / ssum;
        #pragma unroll
        for (int kk = 0; kk < 11; ++kk) w[kk] *= inv;
    }
    {
        float s = 0.f;
        #pragma unroll
        for (int kk = 0; kk < 11; ++kk) s = fmaf(w[kk], hpn[kk][tid], s);
        hattn[tid] = s;
    }
    __syncthreads();
    {
        int c = tid & 127, p = tid >> 7;
        float s = 0.f;
        for (int k = p * 256; k < p * 256 + 256; ++k) {
            float x = (k < 256) ? ht[k] : hattn[k - 256];
            s = fmaf(x, W_edgeT[(size_t)k * 128 + c], s);
        }
        ep[p][c] = s;
    }
    __syncthreads();
    if (tid < 128) {
        float v = ep[0][tid] + ep[1][tid] + b_edge[tid];
        ein_buf[(size_t)row * 128 + tid] = f2bf(v > 0.f ? v : 0.f);
    }
}

// ---------------------------------------------------------------------------
// Node LSTM step, MFMA. M=768 (12 rb x 64 rows), 8 jt -> 96 blocks.
// Block 64x128, 4 waves 2x2, wave 32x64. K=512: nin|ein|h_prev. BK=32, 16 it.
// h state lives in hist (bf16): reads slot t, writes slot t+1.
// ---------------------------------------------------------------------------
__global__ __launch_bounds__(256) void node_mfma(
    int t,
    const u16* __restrict__ nin_all, const u16* __restrict__ ein_buf,
    const u16* __restrict__ WtT_n, const float* __restrict__ bs_n,
    const u16* __restrict__ h_prev, u16* __restrict__ h_cur,
    float* __restrict__ c_n)
{
    const int tid = threadIdx.x;
    const int rb = blockIdx.x >> 3, jt = blockIdx.x & 7;
    const int row0 = rb * 64;

    __shared__ u16 A_lds[64 * 72];
    __shared__ u16 B_lds[128 * 72];

    const int l = tid & 63, wid = tid >> 6;
    const int wm = wid >> 1, wn = wid & 1;
    const int l15 = l & 15, lk = (l >> 4) * 8;

    f32x4 acc[2][4];
    #pragma unroll
    for (int g = 0; g < 4; ++g) {
        float bv = bs_n[jt * 128 + wn * 64 + g * 16 + l15];
        acc[0][g] = (f32x4){bv, bv, bv, bv};
        acc[1][g] = (f32x4){bv, bv, bv, bv};
    }

    const int arow = tid >> 2, aseg = tid & 3;   // 4 threads per 64B A row
    const int brow = tid >> 1, bseg = tid & 1;
    for (int kc = 0; kc < 16; ++kc) {
        const int k0 = kc * 32;
        const u16* asrc;
        if (kc < 4)       asrc = nin_all + ((size_t)t * 768 + row0 + arow) * 128 + k0 + aseg * 8;
        else if (kc < 8)  asrc = ein_buf + (size_t)(row0 + arow) * 128 + (k0 - 128) + aseg * 8;
        else              asrc = h_prev  + (size_t)(row0 + arow) * 256 + (k0 - 256) + aseg * 8;
        float4 a0 = *(const float4*)asrc;
        const u16* bsrc = WtT_n + (size_t)(jt * 128 + brow) * 512 + k0 + bseg * 16;
        float4 b0 = *(const float4*)bsrc;
        float4 b1 = *(const float4*)(bsrc + 8);
        __syncthreads();
        *(float4*)&A_lds[arow * 72 + aseg * 8] = a0;
        *(float4*)&B_lds[brow * 72 + bseg * 16]     = b0;
        *(float4*)&B_lds[brow * 72 + bseg * 16 + 8] = b1;
        __syncthreads();
        bf16x8 afr[2], bfr[4];
        #pragma unroll
        for (int mf = 0; mf < 2; ++mf)
            afr[mf] = *(const bf16x8*)&A_lds[(wm * 32 + mf * 16 + l15) * 72 + lk];
        #pragma unroll
        for (int g = 0; g < 4; ++g)
            bfr[g] = *(const bf16x8*)&B_lds[(wn * 64 + g * 16 + l15) * 72 + lk];
        #pragma unroll
        for (int mf = 0; mf < 2; ++mf)
            #pragma unroll
            for (int g = 0; g < 4; ++g)
                acc[mf][g] = __builtin_amdgcn_mfma_f32_16x16x32_bf16(afr[mf], bfr[g], acc[mf][g], 0, 0, 0);
    }

    const int cell = (jt * 2 + wn) * 16 + l15;
    const int rofs = ((l >> 4) << 2);
    #pragma unroll
    for (int mf = 0; mf < 2; ++mf) {
        int rowb = row0 + wm * 32 + mf * 16 + rofs;
        #pragma unroll
        for (int r = 0; r < 4; ++r) {
            size_t off = (size_t)(rowb + r) * 256 + cell;
            float gi = acc[mf][0][r], gf = acc[mf][1][r], gg = acc[mf][2][r], go = acc[mf][3][r];
            float c2 = sigm(gf) * c_n[off] + sigm(gi) * ftanh(gg);
            float h2 = sigm(go) * ftanh(c2);
            c_n[off] = c2;
            h_cur[off] = f2bf(h2);
        }
    }
}

// out[b,t,n,q] = hist[t+1] . W_out^T + b_out   (hist passed offset by 1 slot)
__global__ __launch_bounds__(256) void out_kernel(
    const u16* __restrict__ hist1, const float* __restrict__ W_out,
    const float* __restrict__ b_out, float* __restrict__ out)
{
    const int lane = threadIdx.x & 63;
    const int grp = threadIdx.x >> 6;
    for (int ridx = blockIdx.x * 4 + grp; ridx < 32 * 768; ridx += gridDim.x * 4) {
        int t = ridx / 768, row = ridx % 768;
        int b = row / 12, n = row % 12;
        const u16* h = &hist1[(size_t)ridx * 256];
        float hv[4];
        #pragma unroll
        for (int i = 0; i < 4; ++i) hv[i] = bf2f(h[i * 64 + lane]);
        #pragma unroll
        for (int q = 0; q < 5; ++q) {
            float s = 0.f;
            #pragma unroll
            for (int i = 0; i < 4; ++i) s = fmaf(hv[i], W_out[q * 256 + i * 64 + lane], s);
            #pragma unroll
            for (int off = 32; off > 0; off >>= 1) s += __shfl_down(s, off, 64);
            if (lane == 0)
                out[(((size_t)b * T_ + t) * N_ + n) * 5 + q] = s + b_out[q];
        }
    }
}

extern "C" void kernel_launch(void* const* d_in, const int* in_sizes, int n_in,
                              void* d_out, int out_size, void* d_ws, size_t ws_size,
                              hipStream_t stream)
{
    const float* nodes = (const float*)d_in[0];
    const float* et    = (const float*)d_in[1];
    const float* es    = (const float*)d_in[2];
    const float* W_te = (const float*)d_in[3];  const float* b_te = (const float*)d_in[4];
    const float* te_Wih = (const float*)d_in[5]; const float* te_Whh = (const float*)d_in[6];
    const float* te_bih = (const float*)d_in[7]; const float* te_bhh = (const float*)d_in[8];
    const float* W_se = (const float*)d_in[9];  const float* b_se = (const float*)d_in[10];
    const float* se_Wih = (const float*)d_in[11]; const float* se_Whh = (const float*)d_in[12];
    const float* se_bih = (const float*)d_in[13]; const float* se_bhh = (const float*)d_in[14];
    const float* Wq = (const float*)d_in[15]; const float* bq = (const float*)d_in[16];
    const float* Wk = (const float*)d_in[17]; const float* bk = (const float*)d_in[18];
    const float* W_node = (const float*)d_in[19]; const float* b_node = (const float*)d_in[20];
    const float* W_edge = (const float*)d_in[21]; const float* b_edge = (const float*)d_in[22];
    const float* nr_Wih = (const float*)d_in[23]; const float* nr_Whh = (const float*)d_in[24];
    const float* nr_bih = (const float*)d_in[25]; const float* nr_bhh = (const float*)d_in[26];
    const float* W_out = (const float*)d_in[27]; const float* b_out = (const float*)d_in[28];

    char* base = (char*)d_ws;
    size_t off = 0;
    auto A = [&](size_t bytes) { char* p = base + off; off += (bytes + 255) & ~(size_t)255; return p; };

    // zero-region 1: fp32 c-states (contiguous)
    float* c_t = (float*)A(768 * 256 * 4);
    float* c_s = (float*)A(8448 * 256 * 4);
    float* c_n = (float*)A(768 * 256 * 4);
    size_t czero_bytes = off;
    // zero-region 2: bf16 h_t[0], h_s[0], hist slot 0 (contiguous)
    u16* h_t0 = (u16*)A(768 * 256 * 2);
    u16* h_s0 = (u16*)A((size_t)8448 * 256 * 2);
    u16* hist = (u16*)A((size_t)33 * 768 * 256 * 2);   // slot 0 = h_node init
    size_t hzero_bytes = ((char*)hist - (char*)h_t0) + (size_t)768 * 256 * 2;
    u16* h_t1 = (u16*)A(768 * 256 * 2);
    u16* h_s1 = (u16*)A((size_t)8448 * 256 * 2);
    u16* ein_bf = (u16*)A(768 * 128 * 2);
    u16* te_all = (u16*)A((size_t)32 * 768 * 128 * 2);
    u16* nin_all = (u16*)A((size_t)32 * 768 * 128 * 2);
    u16* WtT_t = (u16*)A(1024 * 384 * 2);
    u16* WtT_s = (u16*)A(1024 * 384 * 2);
    u16* WtT_n = (u16*)A(1024 * 512 * 2);
    float* bs_t = (float*)A(1024 * 4);
    float* bs_s = (float*)A(1024 * 4);
    float* bs_n = (float*)A(1024 * 4);
    float* WqT = (float*)A(16384 * 4);
    float* WkT = (float*)A(16384 * 4);
    float* W_edgeT = (float*)A(65536 * 4);

    const size_t se_full_bytes = (size_t)32 * 8448 * 128 * 2;
    bool se_full = (off + se_full_bytes + 4096) <= ws_size;
    u16* se_buf = (u16*)A(se_full ? se_full_bytes : (size_t)8448 * 128 * 2);

    hipMemsetAsync(base, 0, czero_bytes, stream);
    hipMemsetAsync(h_t0, 0, hzero_bytes, stream);

    prep_kernel<<<2048, 256, 0, stream>>>(
        te_Wih, te_Whh, te_bih, te_bhh, se_Wih, se_Whh, se_bih, se_bhh,
        nr_Wih, nr_Whh, nr_bih, nr_bhh, Wq, Wk, W_edge,
        WtT_t, WtT_s, WtT_n, bs_t, bs_s, bs_n, WqT, WkT, W_edgeT);

    emb_tn_kernel<<<12288, 256, 0, stream>>>(et, nodes, W_te, b_te, W_node, b_node, te_all, nin_all);

    if (se_full)
        emb_se_kernel<<<32 * 4224, 256, 0, stream>>>(0, es, W_se, b_se, se_buf);

    u16* h_t_pp[2] = {h_t0, h_t1};
    u16* h_s_pp[2] = {h_s0, h_s1};

    for (int t = 0; t < T_; ++t) {
        int pp = t & 1, cc = pp ^ 1;
        const u16* se_step;
        if (se_full) {
            se_step = se_buf + (size_t)t * 8448 * 128;
        } else {
            emb_se_kernel<<<4224, 256, 0, stream>>>(t, es, W_se, b_se, se_buf);
            se_step = se_buf;
        }
        lstm_ts_mfma<<<576, 256, 0, stream>>>(
            t, se_step, te_all, WtT_t, bs_t, WtT_s, bs_s,
            h_t_pp[pp], h_t_pp[cc], c_t, h_s_pp[pp], h_s_pp[cc], c_s);
        attn_kernel<<<768, 256, 0, stream>>>(
            h_t_pp[cc], h_s_pp[cc], WqT, bq, WkT, bk, W_edgeT, b_edge, ein_bf);
        node_mfma<<<96, 256, 0, stream>>>(
            t, nin_all, ein_bf, WtT_n, bs_n,
            hist + (size_t)t * 768 * 256, hist + (size_t)(t + 1) * 768 * 256, c_n);
    }

    out_kernel<<<1536, 256, 0, stream>>>(hist + (size_t)768 * 256, W_out, b_out, (float*)d_out);
}

// Round 3
// 1819.176 us; speedup vs baseline: 3.6190x; 1.0444x over previous
//
#include <hip/hip_runtime.h>
#include <math.h>

#define B_ 64
#define T_ 32
#define N_ 12
#define NS_ 132
#define KN_ 11
#define TEMP_ 1.375f   // K_NEIGH / sqrt(ATTN) = 11/8

typedef unsigned short u16;
typedef __attribute__((ext_vector_type(8))) short bf16x8;
typedef __attribute__((ext_vector_type(8))) unsigned short u16x8;
typedef __attribute__((ext_vector_type(4))) float f32x4;

__device__ __forceinline__ float sigm(float x) { return 1.f / (1.f + __expf(-x)); }
__device__ __forceinline__ float ftanh(float x) {
    float a = fabsf(x);
    float e = __expf(-2.f * a);
    float t = (1.f - e) / (1.f + e);
    return copysignf(t, x);
}
__device__ __forceinline__ u16 f2bf(float x) {
    union { float f; unsigned u; } v; v.f = x;
    unsigned r = v.u + 0x7fffu + ((v.u >> 16) & 1u);
    return (u16)(r >> 16);
}
__device__ __forceinline__ float bf2f(u16 h) {
    union { unsigned u; float f; } v; v.u = ((unsigned)h) << 16; return v.f;
}
// reordered gate-space col j -> original gate col: j = cellhi*64 + gate*16 + celllo
__device__ __forceinline__ int origcol(int j) {
    return ((j >> 4) & 3) * 256 + ((j >> 6) << 4) + (j & 15);
}

// Fragment layout for M[R][K] (A- or B-operand of mfma 16x16x32 bf16):
//   tile = (r>>4)*(K/32) + (k>>5); lane l = ((k>>3)&3)*16 + (r&15); elem = k&7
//   flat u16 index = tile*512 + l*8 + elem
// Wave load: 64 lanes x 16B contiguous per tile (1KB burst).

// ---------------------------------------------------------------------------
// prep: weights -> bf16 fragment layout, fused biases, attn weights -> bf16.
// 65536 threads (256 blocks).
// ---------------------------------------------------------------------------
__global__ __launch_bounds__(256) void prep_kernel(
    const float* __restrict__ te_Wih, const float* __restrict__ te_Whh,
    const float* __restrict__ te_bih, const float* __restrict__ te_bhh,
    const float* __restrict__ se_Wih, const float* __restrict__ se_Whh,
    const float* __restrict__ se_bih, const float* __restrict__ se_bhh,
    const float* __restrict__ nr_Wih, const float* __restrict__ nr_Whh,
    const float* __restrict__ nr_bih, const float* __restrict__ nr_bhh,
    const float* __restrict__ Wq, const float* __restrict__ Wk,
    const float* __restrict__ W_edge,
    u16* __restrict__ Wf_t, u16* __restrict__ Wf_s, u16* __restrict__ Wf_n,
    float* __restrict__ bs_t, float* __restrict__ bs_s, float* __restrict__ bs_n,
    u16* __restrict__ Wq_bf, u16* __restrict__ Wk_bf, u16* __restrict__ We_bf)
{
    int idx = blockIdx.x * 256 + threadIdx.x;
    if (idx < 49152) {                 // Wf_t / Wf_s: 64 jb16 x 12 kc x 64 lanes
        int l = idx & 63, kc = (idx >> 6) % 12, jb16 = idx / 768;
        int j = jb16 * 16 + (l & 15);
        int c = origcol(j);
        int k0 = kc * 32 + (l >> 4) * 8;
        u16x8 vt, vs;
        #pragma unroll
        for (int i = 0; i < 8; ++i) {
            int k = k0 + i;
            vt[i] = f2bf((k < 128) ? te_Wih[c * 128 + k] : te_Whh[c * 256 + (k - 128)]);
            vs[i] = f2bf((k < 128) ? se_Wih[c * 128 + k] : se_Whh[c * 256 + (k - 128)]);
        }
        *(u16x8*)(Wf_t + (size_t)idx * 8) = vt;
        *(u16x8*)(Wf_s + (size_t)idx * 8) = vs;
    }
    if (idx < 65536) {                 // Wf_n: 64 jb16 x 16 kc x 64 lanes
        int l = idx & 63, kc = (idx >> 6) & 15, jb16 = idx >> 10;
        int j = jb16 * 16 + (l & 15);
        int c = origcol(j);
        int k0 = kc * 32 + (l >> 4) * 8;
        u16x8 vn;
        #pragma unroll
        for (int i = 0; i < 8; ++i) {
            int k = k0 + i;
            vn[i] = f2bf((k < 256) ? nr_Wih[c * 256 + k] : nr_Whh[c * 256 + (k - 256)]);
        }
        *(u16x8*)(Wf_n + (size_t)idx * 8) = vn;
    }
    if (idx < 1024) {
        int c = origcol(idx);
        bs_t[idx] = te_bih[c] + te_bhh[c];
        bs_s[idx] = se_bih[c] + se_bhh[c];
        bs_n[idx] = nr_bih[c] + nr_bhh[c];
    }
    if (idx < 16384) {                 // [k][a] bf16
        int k = idx >> 6, a = idx & 63;
        Wq_bf[idx] = f2bf(Wq[a * 256 + k]);
        Wk_bf[idx] = f2bf(Wk[a * 256 + k]);
    }
    if (idx < 65536) {                 // [k][c] bf16
        int k = idx >> 7, c = idx & 127;
        We_bf[idx] = f2bf(W_edge[c * 512 + k]);
    }
}

// te/nin embeddings in fragment layout: u = ((t*48+rb16)*4+kc)*64 + l
__global__ __launch_bounds__(256) void emb_tn_kernel(
    const float* __restrict__ et, const float* __restrict__ nodes,
    const float* __restrict__ W_te, const float* __restrict__ b_te,
    const float* __restrict__ W_node, const float* __restrict__ b_node,
    u16* __restrict__ tef, u16* __restrict__ ninf)
{
    int u = blockIdx.x * 256 + threadIdx.x;   // 32*48*4*64 = 393216 exact
    int l = u & 63, kc = (u >> 6) & 3;
    int rt = u >> 8;
    int rb16 = rt % 48, t = rt / 48;
    int row = rb16 * 16 + (l & 15);
    int b = row / 12, n = row - b * 12;
    size_t src = (((size_t)b * T_ + t) * N_ + n) * 2;
    float e0 = et[src], e1 = et[src + 1];
    float n0 = nodes[src], n1 = nodes[src + 1];
    int k0 = kc * 32 + (l >> 4) * 8;
    u16x8 vt, vn;
    #pragma unroll
    for (int i = 0; i < 8; ++i) {
        int k = k0 + i;
        float x = fmaf(e0, W_te[k * 2], fmaf(e1, W_te[k * 2 + 1], b_te[k]));
        vt[i] = f2bf(fmaxf(x, 0.f));
        float y = fmaf(n0, W_node[k * 2], fmaf(n1, W_node[k * 2 + 1], b_node[k]));
        vn[i] = f2bf(fmaxf(y, 0.f));
    }
    *(u16x8*)(tef + (size_t)u * 8) = vt;
    *(u16x8*)(ninf + (size_t)u * 8) = vn;
}

// spatial embeddings, fragment layout: u = ((trel*528+rb16)*4+kc)*64 + l
__global__ __launch_bounds__(256) void emb_se_kernel(
    int t0, const float* __restrict__ es,
    const float* __restrict__ W_se, const float* __restrict__ b_se,
    u16* __restrict__ sef)
{
    int u = blockIdx.x * 256 + threadIdx.x;   // tcount*528*4*64, exact
    int l = u & 63, kc = (u >> 6) & 3;
    int rt = u >> 8;
    int rb16 = rt % 528, trel = rt / 528;
    int row = rb16 * 16 + (l & 15);
    int b = row / NS_, s = row - b * NS_;
    size_t src = (((size_t)b * T_ + (t0 + trel)) * NS_ + s) * 2;
    float e0 = es[src], e1 = es[src + 1];
    int k0 = kc * 32 + (l >> 4) * 8;
    u16x8 v;
    #pragma unroll
    for (int i = 0; i < 8; ++i) {
        int k = k0 + i;
        float x = fmaf(e0, W_se[k * 2], fmaf(e1, W_se[k * 2 + 1], b_se[k]));
        v[i] = f2bf(fmaxf(x, 0.f));
    }
    *(u16x8*)(sef + (size_t)u * 8) = v;
}

// ---------------------------------------------------------------------------
// Fused temporal+spatial LSTM step — fragment-direct MFMA, no LDS, no barriers.
// 576 blocks (528 spatial XCD-swizzled + 48 temporal), 4 waves of 64x64 tiles.
// K = 384: kc 0-3 emb frag, kc 4-11 h frag. Dual-write epilogue (dense+frag).
// ---------------------------------------------------------------------------
__global__ __launch_bounds__(256) void lstm_ts_mfma(
    const u16* __restrict__ sef_step, const u16* __restrict__ tef_step,
    const u16* __restrict__ Wf_t, const float* __restrict__ bs_t,
    const u16* __restrict__ Wf_s, const float* __restrict__ bs_s,
    const u16* __restrict__ htf_p, u16* __restrict__ htf_c, u16* __restrict__ ht_d,
    float* __restrict__ c_t,
    const u16* __restrict__ hsf_p, u16* __restrict__ hsf_c, u16* __restrict__ hs_d,
    float* __restrict__ c_s)
{
    const int tid = threadIdx.x;
    const bool spatial = blockIdx.x < 528;
    int rb, jc;
    if (spatial) {
        int orig = (blockIdx.x & 7) * 66 + (blockIdx.x >> 3);   // XCD owns contiguous rows
        rb = orig >> 3; jc = orig & 7;
    } else {
        int q = blockIdx.x - 528;
        rb = q >> 3; jc = q & 7;
    }
    const u16* Ef = spatial ? sef_step : tef_step;
    const u16* Hf = spatial ? hsf_p : htf_p;
    const u16* Wf = spatial ? Wf_s : Wf_t;
    const float* bs = spatial ? bs_s : bs_t;
    u16* Hfc = spatial ? hsf_c : htf_c;
    u16* Hd  = spatial ? hs_d : ht_d;
    float* C  = spatial ? c_s : c_t;

    const int l = tid & 63, wid = tid >> 6;
    const int wm = wid >> 1, wn = wid & 1;
    const int l15 = l & 15;
    const int rb16 = rb * 8 + wm * 4;     // + mf
    const int jb16 = jc * 8 + wn * 4;     // + g
    const size_t lo8 = (size_t)l * 8;

    f32x4 acc[4][4];
    #pragma unroll
    for (int g = 0; g < 4; ++g) {
        float bv = bs[jc * 128 + wn * 64 + g * 16 + l15];
        #pragma unroll
        for (int mf = 0; mf < 4; ++mf) acc[mf][g] = (f32x4){bv, bv, bv, bv};
    }

    auto loadA = [&](int kc, bf16x8* a) {
        #pragma unroll
        for (int mf = 0; mf < 4; ++mf) {
            const u16* p = (kc < 4)
                ? Ef + (((size_t)(rb16 + mf)) * 4 + kc) * 512 + lo8
                : Hf + (((size_t)(rb16 + mf)) * 8 + (kc - 4)) * 512 + lo8;
            a[mf] = *(const bf16x8*)p;
        }
    };
    auto loadB = [&](int kc, bf16x8* b) {
        #pragma unroll
        for (int g = 0; g < 4; ++g)
            b[g] = *(const bf16x8*)(Wf + (((size_t)(jb16 + g)) * 12 + kc) * 512 + lo8);
    };
    auto domfma = [&](bf16x8* a, bf16x8* b) {
        #pragma unroll
        for (int mf = 0; mf < 4; ++mf)
            #pragma unroll
            for (int g = 0; g < 4; ++g)
                acc[mf][g] = __builtin_amdgcn_mfma_f32_16x16x32_bf16(a[mf], b[g], acc[mf][g], 0, 0, 0);
    };

    bf16x8 a0[4], b0[4], a1[4], b1[4];
    loadA(0, a0); loadB(0, b0);
    #pragma unroll
    for (int kc = 0; kc < 12; kc += 2) {
        loadA(kc + 1, a1); loadB(kc + 1, b1);
        domfma(a0, b0);
        if (kc + 2 < 12) { loadA(kc + 2, a0); loadB(kc + 2, b0); }
        domfma(a1, b1);
    }

    // epilogue: thread owns all 4 gates of cell = (jc*2+wn)*16 + l15
    const int cell = (jc * 2 + wn) * 16 + l15;
    const int rofs = (l >> 4) << 2;
    const int cpart = (cell >> 5) * 512 + ((cell >> 3) & 3) * 128 + (cell & 7);
    #pragma unroll
    for (int mf = 0; mf < 4; ++mf) {
        int r16 = rb16 + mf;
        #pragma unroll
        for (int r = 0; r < 4; ++r) {
            int rlow = rofs + r;
            size_t doff = ((size_t)r16 * 16 + rlow) * 256 + cell;
            float gi = acc[mf][0][r], gf = acc[mf][1][r], gg = acc[mf][2][r], go = acc[mf][3][r];
            float c2 = sigm(gf) * C[doff] + sigm(gi) * ftanh(gg);
            float h2 = sigm(go) * ftanh(c2);
            C[doff] = c2;
            u16 hb = f2bf(h2);
            Hd[doff] = hb;
            Hfc[(size_t)r16 * 4096 + cpart + rlow * 8] = hb;
        }
    }
}

// ---------------------------------------------------------------------------
// Attention + edge-input per (b,n). bf16 weights; ein written in frag layout.
// ---------------------------------------------------------------------------
__global__ __launch_bounds__(256) void attn_kernel(
    const u16* __restrict__ ht_d, const u16* __restrict__ hs_d,
    const u16* __restrict__ Wq_bf, const float* __restrict__ bq,
    const u16* __restrict__ Wk_bf, const float* __restrict__ bk,
    const u16* __restrict__ We_bf, const float* __restrict__ b_edge,
    u16* __restrict__ einf)
{
    const int tid = threadIdx.x;
    const int b = blockIdx.x / N_, n = blockIdx.x % N_;
    const int row = blockIdx.x;

    __shared__ float ht[256];
    __shared__ float hpn[11][256];
    __shared__ float qp[4][64];
    __shared__ float qv[64];
    __shared__ float qk[256];
    __shared__ float scp[11][16];
    __shared__ float sc[11];
    __shared__ float hattn[256];
    __shared__ float ep[2][128];

    ht[tid] = bf2f(ht_d[(size_t)row * 256 + tid]);
    const int base = b * NS_ + n * KN_;
    #pragma unroll
    for (int kk = 0; kk < 11; ++kk)
        hpn[kk][tid] = bf2f(hs_d[(size_t)(base + kk) * 256 + tid]);
    __syncthreads();

    {
        int a = tid & 63, p = tid >> 6;
        float s = 0.f;
        for (int k = p * 64; k < p * 64 + 64; ++k)
            s = fmaf(ht[k], bf2f(Wq_bf[k * 64 + a]), s);
        qp[p][a] = s;
    }
    __syncthreads();
    if (tid < 64) qv[tid] = bq[tid] + qp[0][tid] + qp[1][tid] + qp[2][tid] + qp[3][tid];
    __syncthreads();
    {
        float s = 0.f;
        for (int a = 0; a < 64; ++a) s = fmaf(qv[a], bf2f(Wk_bf[tid * 64 + a]), s);
        qk[tid] = s;
    }
    float qb = 0.f;
    for (int a = 0; a < 64; ++a) qb = fmaf(qv[a], bk[a], qb);
    __syncthreads();
    if (tid < 176) {
        int kk = tid >> 4, p = tid & 15;
        float s = 0.f;
        for (int k = p * 16; k < p * 16 + 16; ++k)
            s = fmaf(qk[k], hpn[kk][k], s);
        scp[kk][p] = s;
    }
    __syncthreads();
    if (tid < 11) {
        float s = 0.f;
        #pragma unroll
        for (int p = 0; p < 16; ++p) s += scp[tid][p];
        sc[tid] = (s + qb) * TEMP_;
    }
    __syncthreads();

    float w[11];
    {
        float m = sc[0];
        #pragma unroll
        for (int kk = 1; kk < 11; ++kk) m = fmaxf(m, sc[kk]);
        float ssum = 0.f;
        #pragma unroll
        for (int kk = 0; kk < 11; ++kk) { w[kk] = __expf(sc[kk] - m); ssum += w[kk]; }
        float inv = 1.f / ssum;
        #pragma unroll
        for (int kk = 0; kk < 11; ++kk) w[kk] *= inv;
    }
    {
        float s = 0.f;
        #pragma unroll
        for (int kk = 0; kk < 11; ++kk) s = fmaf(w[kk], hpn[kk][tid], s);
        hattn[tid] = s;
    }
    __syncthreads();
    {
        int c = tid & 127, p = tid >> 7;
        float s = 0.f;
        for (int k = p * 256; k < p * 256 + 256; ++k) {
            float x = (k < 256) ? ht[k] : hattn[k - 256];
            s = fmaf(x, bf2f(We_bf[(size_t)k * 128 + c]), s);
        }
        ep[p][c] = s;
    }
    __syncthreads();
    if (tid < 128) {
        float v = ep[0][tid] + ep[1][tid] + b_edge[tid];
        int cell = tid;
        size_t fo = (((size_t)(row >> 4)) * 4 + (cell >> 5)) * 512
                  + (((cell >> 3) & 3) * 16 + (row & 15)) * 8 + (cell & 7);
        einf[fo] = f2bf(v > 0.f ? v : 0.f);
    }
}

// ---------------------------------------------------------------------------
// Node LSTM step — fragment-direct MFMA. 96 blocks (12 rb x 8 jc), waves 32x64.
// K = 512: kc 0-3 nin frag, 4-7 ein frag, 8-15 h_node frag.
// ---------------------------------------------------------------------------
__global__ __launch_bounds__(256) void node_mfma(
    const u16* __restrict__ ninf_t, const u16* __restrict__ einf,
    const u16* __restrict__ Wf_n, const float* __restrict__ bs_n,
    const u16* __restrict__ hnf_p, u16* __restrict__ hnf_c,
    u16* __restrict__ hist1,   // dense hist slot t+1
    float* __restrict__ c_n)
{
    const int tid = threadIdx.x;
    const int rb = blockIdx.x >> 3, jc = blockIdx.x & 7;

    const int l = tid & 63, wid = tid >> 6;
    const int wm = wid >> 1, wn = wid & 1;
    const int l15 = l & 15;
    const int rb16 = rb * 4 + wm * 2;    // + mf
    const int jb16 = jc * 8 + wn * 4;    // + g
    const size_t lo8 = (size_t)l * 8;

    f32x4 acc[2][4];
    #pragma unroll
    for (int g = 0; g < 4; ++g) {
        float bv = bs_n[jc * 128 + wn * 64 + g * 16 + l15];
        acc[0][g] = (f32x4){bv, bv, bv, bv};
        acc[1][g] = (f32x4){bv, bv, bv, bv};
    }

    auto loadA = [&](int kc, bf16x8* a) {
        #pragma unroll
        for (int mf = 0; mf < 2; ++mf) {
            size_t r16 = rb16 + mf;
            const u16* p;
            if (kc < 4)       p = ninf_t + (r16 * 4 + kc) * 512 + lo8;
            else if (kc < 8)  p = einf   + (r16 * 4 + (kc - 4)) * 512 + lo8;
            else              p = hnf_p  + (r16 * 8 + (kc - 8)) * 512 + lo8;
            a[mf] = *(const bf16x8*)p;
        }
    };
    auto loadB = [&](int kc, bf16x8* b) {
        #pragma unroll
        for (int g = 0; g < 4; ++g)
            b[g] = *(const bf16x8*)(Wf_n + (((size_t)(jb16 + g)) * 16 + kc) * 512 + lo8);
    };
    auto domfma = [&](bf16x8* a, bf16x8* b) {
        #pragma unroll
        for (int mf = 0; mf < 2; ++mf)
            #pragma unroll
            for (int g = 0; g < 4; ++g)
                acc[mf][g] = __builtin_amdgcn_mfma_f32_16x16x32_bf16(a[mf], b[g], acc[mf][g], 0, 0, 0);
    };

    bf16x8 a0[2], b0[4], a1[2], b1[4];
    loadA(0, a0); loadB(0, b0);
    #pragma unroll
    for (int kc = 0; kc < 16; kc += 2) {
        loadA(kc + 1, a1); loadB(kc + 1, b1);
        domfma(a0, b0);
        if (kc + 2 < 16) { loadA(kc + 2, a0); loadB(kc + 2, b0); }
        domfma(a1, b1);
    }

    const int cell = (jc * 2 + wn) * 16 + l15;
    const int rofs = (l >> 4) << 2;
    const int cpart = (cell >> 5) * 512 + ((cell >> 3) & 3) * 128 + (cell & 7);
    #pragma unroll
    for (int mf = 0; mf < 2; ++mf) {
        int r16 = rb16 + mf;
        #pragma unroll
        for (int r = 0; r < 4; ++r) {
            int rlow = rofs + r;
            size_t doff = ((size_t)r16 * 16 + rlow) * 256 + cell;
            float gi = acc[mf][0][r], gf = acc[mf][1][r], gg = acc[mf][2][r], go = acc[mf][3][r];
            float c2 = sigm(gf) * c_n[doff] + sigm(gi) * ftanh(gg);
            float h2 = sigm(go) * ftanh(c2);
            c_n[doff] = c2;
            u16 hb = f2bf(h2);
            hist1[doff] = hb;
            hnf_c[(size_t)r16 * 4096 + cpart + rlow * 8] = hb;
        }
    }
}

// out[b,t,n,q] = hist[t+1] . W_out^T + b_out
__global__ __launch_bounds__(256) void out_kernel(
    const u16* __restrict__ hist1, const float* __restrict__ W_out,
    const float* __restrict__ b_out, float* __restrict__ out)
{
    const int lane = threadIdx.x & 63;
    const int grp = threadIdx.x >> 6;
    for (int ridx = blockIdx.x * 4 + grp; ridx < 32 * 768; ridx += gridDim.x * 4) {
        int t = ridx / 768, row = ridx % 768;
        int b = row / 12, n = row % 12;
        const u16* h = &hist1[(size_t)ridx * 256];
        float hv[4];
        #pragma unroll
        for (int i = 0; i < 4; ++i) hv[i] = bf2f(h[i * 64 + lane]);
        #pragma unroll
        for (int q = 0; q < 5; ++q) {
            float s = 0.f;
            #pragma unroll
            for (int i = 0; i < 4; ++i) s = fmaf(hv[i], W_out[q * 256 + i * 64 + lane], s);
            #pragma unroll
            for (int off = 32; off > 0; off >>= 1) s += __shfl_down(s, off, 64);
            if (lane == 0)
                out[(((size_t)b * T_ + t) * N_ + n) * 5 + q] = s + b_out[q];
        }
    }
}

extern "C" void kernel_launch(void* const* d_in, const int* in_sizes, int n_in,
                              void* d_out, int out_size, void* d_ws, size_t ws_size,
                              hipStream_t stream)
{
    const float* nodes = (const float*)d_in[0];
    const float* et    = (const float*)d_in[1];
    const float* es    = (const float*)d_in[2];
    const float* W_te = (const float*)d_in[3];  const float* b_te = (const float*)d_in[4];
    const float* te_Wih = (const float*)d_in[5]; const float* te_Whh = (const float*)d_in[6];
    const float* te_bih = (const float*)d_in[7]; const float* te_bhh = (const float*)d_in[8];
    const float* W_se = (const float*)d_in[9];  const float* b_se = (const float*)d_in[10];
    const float* se_Wih = (const float*)d_in[11]; const float* se_Whh = (const float*)d_in[12];
    const float* se_bih = (const float*)d_in[13]; const float* se_bhh = (const float*)d_in[14];
    const float* Wq = (const float*)d_in[15]; const float* bq = (const float*)d_in[16];
    const float* Wk = (const float*)d_in[17]; const float* bk = (const float*)d_in[18];
    const float* W_node = (const float*)d_in[19]; const float* b_node = (const float*)d_in[20];
    const float* W_edge = (const float*)d_in[21]; const float* b_edge = (const float*)d_in[22];
    const float* nr_Wih = (const float*)d_in[23]; const float* nr_Whh = (const float*)d_in[24];
    const float* nr_bih = (const float*)d_in[25]; const float* nr_bhh = (const float*)d_in[26];
    const float* W_out = (const float*)d_in[27]; const float* b_out = (const float*)d_in[28];

    char* base = (char*)d_ws;
    size_t off = 0;
    auto A = [&](size_t bytes) { char* p = base + off; off += (bytes + 255) & ~(size_t)255; return p; };

    // ---- zero region: c-states (f32) + t=0 frag h-states (bf16), contiguous ----
    float* c_t = (float*)A(768 * 256 * 4);
    float* c_s = (float*)A((size_t)8448 * 256 * 4);
    float* c_n = (float*)A(768 * 256 * 4);
    u16* htf0 = (u16*)A(768 * 256 * 2);
    u16* hsf0 = (u16*)A((size_t)8448 * 256 * 2);
    u16* hnf0 = (u16*)A(768 * 256 * 2);
    size_t zero_bytes = off;
    // ---- rest ----
    u16* htf1 = (u16*)A(768 * 256 * 2);
    u16* hsf1 = (u16*)A((size_t)8448 * 256 * 2);
    u16* hnf1 = (u16*)A(768 * 256 * 2);
    u16* ht_d = (u16*)A(768 * 256 * 2);
    u16* hs_d = (u16*)A((size_t)8448 * 256 * 2);
    u16* hist = (u16*)A((size_t)33 * 768 * 256 * 2);   // slots 1..32 used
    u16* einf = (u16*)A(768 * 128 * 2);
    u16* tef  = (u16*)A((size_t)32 * 768 * 128 * 2);
    u16* ninf = (u16*)A((size_t)32 * 768 * 128 * 2);
    u16* Wf_t = (u16*)A(1024 * 384 * 2);
    u16* Wf_s = (u16*)A(1024 * 384 * 2);
    u16* Wf_n = (u16*)A(1024 * 512 * 2);
    float* bs_t = (float*)A(1024 * 4);
    float* bs_s = (float*)A(1024 * 4);
    float* bs_n = (float*)A(1024 * 4);
    u16* Wq_bf = (u16*)A(16384 * 2);
    u16* Wk_bf = (u16*)A(16384 * 2);
    u16* We_bf = (u16*)A(65536 * 2);

    const size_t sef_full_bytes = (size_t)32 * 8448 * 128 * 2;
    bool sef_full = (off + sef_full_bytes + 4096) <= ws_size;
    u16* sef = (u16*)A(sef_full ? sef_full_bytes : (size_t)8448 * 128 * 2);

    hipMemsetAsync(base, 0, zero_bytes, stream);

    prep_kernel<<<256, 256, 0, stream>>>(
        te_Wih, te_Whh, te_bih, te_bhh, se_Wih, se_Whh, se_bih, se_bhh,
        nr_Wih, nr_Whh, nr_bih, nr_bhh, Wq, Wk, W_edge,
        Wf_t, Wf_s, Wf_n, bs_t, bs_s, bs_n, Wq_bf, Wk_bf, We_bf);

    emb_tn_kernel<<<1536, 256, 0, stream>>>(et, nodes, W_te, b_te, W_node, b_node, tef, ninf);

    if (sef_full)
        emb_se_kernel<<<16896, 256, 0, stream>>>(0, es, W_se, b_se, sef);

    u16* htf[2] = {htf0, htf1};
    u16* hsf[2] = {hsf0, hsf1};
    u16* hnf[2] = {hnf0, hnf1};

    for (int t = 0; t < T_; ++t) {
        int pp = t & 1, cc = pp ^ 1;
        const u16* sef_step;
        if (sef_full) {
            sef_step = sef + (size_t)t * 528 * 4 * 512;
        } else {
            emb_se_kernel<<<528, 256, 0, stream>>>(t, es, W_se, b_se, sef);
            sef_step = sef;
        }
        lstm_ts_mfma<<<576, 256, 0, stream>>>(
            sef_step, tef + (size_t)t * 48 * 4 * 512,
            Wf_t, bs_t, Wf_s, bs_s,
            htf[pp], htf[cc], ht_d, c_t,
            hsf[pp], hsf[cc], hs_d, c_s);
        attn_kernel<<<768, 256, 0, stream>>>(
            ht_d, hs_d, Wq_bf, bq, Wk_bf, bk, We_bf, b_edge, einf);
        node_mfma<<<96, 256, 0, stream>>>(
            ninf + (size_t)t * 48 * 4 * 512, einf, Wf_n, bs_n,
            hnf[pp], hnf[cc], hist + (size_t)(t + 1) * 768 * 256, c_n);
    }

    out_kernel<<<1536, 256, 0, stream>>>(hist + (size_t)768 * 256, W_out, b_out, (float*)d_out);
}

// Round 4
// 1572.596 us; speedup vs baseline: 4.1864x; 1.1568x over previous
//
#include <hip/hip_runtime.h>
#include <math.h>

#define B_ 64
#define T_ 32
#define N_ 12
#define NS_ 132
#define KN_ 11
#define TEMP_ 1.375f   // K_NEIGH / sqrt(ATTN) = 11/8

typedef unsigned short u16;
typedef __attribute__((ext_vector_type(8))) short bf16x8;
typedef __attribute__((ext_vector_type(8))) unsigned short u16x8;
typedef __attribute__((ext_vector_type(4))) float f32x4;

__device__ __forceinline__ float sigm(float x) { return 1.f / (1.f + __expf(-x)); }
__device__ __forceinline__ float ftanh(float x) {
    float a = fabsf(x);
    float e = __expf(-2.f * a);
    float t = (1.f - e) / (1.f + e);
    return copysignf(t, x);
}
__device__ __forceinline__ u16 f2bf(float x) {
    union { float f; unsigned u; } v; v.f = x;
    unsigned r = v.u + 0x7fffu + ((v.u >> 16) & 1u);
    return (u16)(r >> 16);
}
__device__ __forceinline__ float bf2f(u16 h) {
    union { unsigned u; float f; } v; v.u = ((unsigned)h) << 16; return v.f;
}
// reordered gate-space col j -> original gate col: j = cellhi*64 + gate*16 + celllo
__device__ __forceinline__ int origcol(int j) {
    return ((j >> 4) & 3) * 256 + ((j >> 6) << 4) + (j & 15);
}

// Fragment layout for M[R][K] (A/B operand of mfma 16x16x32 bf16):
//   tile = (r>>4)*(K/32) + (k>>5); lane = ((k>>3)&3)*16 + (r&15); elem = k&7
//   flat u16 index = tile*512 + lane*8 + elem

// ---------------------------------------------------------------------------
// prep: all weights -> bf16 fragment layout, fused biases.
// ---------------------------------------------------------------------------
__global__ __launch_bounds__(256) void prep_kernel(
    const float* __restrict__ te_Wih, const float* __restrict__ te_Whh,
    const float* __restrict__ te_bih, const float* __restrict__ te_bhh,
    const float* __restrict__ se_Wih, const float* __restrict__ se_Whh,
    const float* __restrict__ se_bih, const float* __restrict__ se_bhh,
    const float* __restrict__ nr_Wih, const float* __restrict__ nr_Whh,
    const float* __restrict__ nr_bih, const float* __restrict__ nr_bhh,
    const float* __restrict__ Wq, const float* __restrict__ Wk,
    const float* __restrict__ W_edge,
    u16* __restrict__ Wf_t, u16* __restrict__ Wf_s, u16* __restrict__ Wf_n,
    float* __restrict__ bs_t, float* __restrict__ bs_s, float* __restrict__ bs_n,
    u16* __restrict__ Wqf, u16* __restrict__ Wkqf, u16* __restrict__ Wef)
{
    int idx = blockIdx.x * 256 + threadIdx.x;
    if (idx < 49152) {                 // Wf_t / Wf_s: 64 jb16 x 12 kc x 64 lanes
        int l = idx & 63, kc = (idx >> 6) % 12, jb16 = idx / 768;
        int j = jb16 * 16 + (l & 15);
        int c = origcol(j);
        int k0 = kc * 32 + (l >> 4) * 8;
        u16x8 vt, vs;
        #pragma unroll
        for (int i = 0; i < 8; ++i) {
            int k = k0 + i;
            vt[i] = f2bf((k < 128) ? te_Wih[c * 128 + k] : te_Whh[c * 256 + (k - 128)]);
            vs[i] = f2bf((k < 128) ? se_Wih[c * 128 + k] : se_Whh[c * 256 + (k - 128)]);
        }
        *(u16x8*)(Wf_t + (size_t)idx * 8) = vt;
        *(u16x8*)(Wf_s + (size_t)idx * 8) = vs;
    }
    if (idx < 65536) {                 // Wf_n: 64 jb16 x 16 kc x 64 lanes
        int l = idx & 63, kc = (idx >> 6) & 15, jb16 = idx >> 10;
        int j = jb16 * 16 + (l & 15);
        int c = origcol(j);
        int k0 = kc * 32 + (l >> 4) * 8;
        u16x8 vn;
        #pragma unroll
        for (int i = 0; i < 8; ++i) {
            int k = k0 + i;
            vn[i] = f2bf((k < 256) ? nr_Wih[c * 256 + k] : nr_Whh[c * 256 + (k - 256)]);
        }
        *(u16x8*)(Wf_n + (size_t)idx * 8) = vn;
    }
    if (idx < 1024) {
        int c = origcol(idx);
        bs_t[idx] = te_bih[c] + te_bhh[c];
        bs_s[idx] = se_bih[c] + se_bhh[c];
        bs_n[idx] = nr_bih[c] + nr_bhh[c];
    }
    if (idx < 2048) {                  // Wqf: B[a][k], a<64, K=256 -> 4 jb x 8 kc
        int l = idx & 63, tile = idx >> 6;
        int a = (tile >> 3) * 16 + (l & 15);
        int k0 = (tile & 7) * 32 + (l >> 4) * 8;
        u16x8 v;
        #pragma unroll
        for (int i = 0; i < 8; ++i) v[i] = f2bf(Wq[a * 256 + k0 + i]);
        *(u16x8*)(Wqf + (size_t)idx * 8) = v;
    }
    if (idx < 2048) {                  // Wkqf: B[j][a] = Wk[a][j], j<256, K=64 -> 16 jb x 2 kc
        int l = idx & 63, tile = idx >> 6;
        int j = (tile >> 1) * 16 + (l & 15);
        int a0 = (tile & 1) * 32 + (l >> 4) * 8;
        u16x8 v;
        #pragma unroll
        for (int i = 0; i < 8; ++i) v[i] = f2bf(Wk[(a0 + i) * 256 + j]);
        *(u16x8*)(Wkqf + (size_t)idx * 8) = v;
    }
    if (idx < 8192) {                  // Wef: B[c][k], c<128, K=512 -> 8 jb x 16 kc
        int l = idx & 63, tile = idx >> 6;
        int c = (tile >> 4) * 16 + (l & 15);
        int k0 = (tile & 15) * 32 + (l >> 4) * 8;
        u16x8 v;
        #pragma unroll
        for (int i = 0; i < 8; ++i) v[i] = f2bf(W_edge[c * 512 + k0 + i]);
        *(u16x8*)(Wef + (size_t)idx * 8) = v;
    }
}

// te/nin embeddings in fragment layout: u = ((t*48+rb16)*4+kc)*64 + l
__global__ __launch_bounds__(256) void emb_tn_kernel(
    const float* __restrict__ et, const float* __restrict__ nodes,
    const float* __restrict__ W_te, const float* __restrict__ b_te,
    const float* __restrict__ W_node, const float* __restrict__ b_node,
    u16* __restrict__ tef, u16* __restrict__ ninf)
{
    int u = blockIdx.x * 256 + threadIdx.x;   // 32*48*4*64 = 393216 exact
    int l = u & 63, kc = (u >> 6) & 3;
    int rt = u >> 8;
    int rb16 = rt % 48, t = rt / 48;
    int row = rb16 * 16 + (l & 15);
    int b = row / 12, n = row - b * 12;
    size_t src = (((size_t)b * T_ + t) * N_ + n) * 2;
    float e0 = et[src], e1 = et[src + 1];
    float n0 = nodes[src], n1 = nodes[src + 1];
    int k0 = kc * 32 + (l >> 4) * 8;
    u16x8 vt, vn;
    #pragma unroll
    for (int i = 0; i < 8; ++i) {
        int k = k0 + i;
        float x = fmaf(e0, W_te[k * 2], fmaf(e1, W_te[k * 2 + 1], b_te[k]));
        vt[i] = f2bf(fmaxf(x, 0.f));
        float y = fmaf(n0, W_node[k * 2], fmaf(n1, W_node[k * 2 + 1], b_node[k]));
        vn[i] = f2bf(fmaxf(y, 0.f));
    }
    *(u16x8*)(tef + (size_t)u * 8) = vt;
    *(u16x8*)(ninf + (size_t)u * 8) = vn;
}

// spatial embeddings, fragment layout: u = ((trel*528+rb16)*4+kc)*64 + l
__global__ __launch_bounds__(256) void emb_se_kernel(
    int t0, const float* __restrict__ es,
    const float* __restrict__ W_se, const float* __restrict__ b_se,
    u16* __restrict__ sef)
{
    int u = blockIdx.x * 256 + threadIdx.x;
    int l = u & 63, kc = (u >> 6) & 3;
    int rt = u >> 8;
    int rb16 = rt % 528, trel = rt / 528;
    int row = rb16 * 16 + (l & 15);
    int b = row / NS_, s = row - b * NS_;
    size_t src = (((size_t)b * T_ + (t0 + trel)) * NS_ + s) * 2;
    float e0 = es[src], e1 = es[src + 1];
    int k0 = kc * 32 + (l >> 4) * 8;
    u16x8 v;
    #pragma unroll
    for (int i = 0; i < 8; ++i) {
        int k = k0 + i;
        float x = fmaf(e0, W_se[k * 2], fmaf(e1, W_se[k * 2 + 1], b_se[k]));
        v[i] = f2bf(fmaxf(x, 0.f));
    }
    *(u16x8*)(sef + (size_t)u * 8) = v;
}

// ---------------------------------------------------------------------------
// D2: blocks [0, nlstm) = temporal+spatial LSTM step t ; blocks [nlstm, +192)
// = node LSTM step t_node (runs concurrently; disjoint buffers).
// ---------------------------------------------------------------------------
__global__ __launch_bounds__(256) void lstm_node_kernel(
    int nlstm, int t_node,
    const u16* __restrict__ sef_step, const u16* __restrict__ tef_step,
    const u16* __restrict__ Wf_t, const float* __restrict__ bs_t,
    const u16* __restrict__ Wf_s, const float* __restrict__ bs_s,
    const u16* __restrict__ htf_p, u16* __restrict__ htf_c, u16* __restrict__ ht_d,
    float* __restrict__ c_t,
    const u16* __restrict__ hsf_p, u16* __restrict__ hsf_c, u16* __restrict__ hs_d,
    float* __restrict__ c_s,
    const u16* __restrict__ ninf_t, const u16* __restrict__ einf,
    const u16* __restrict__ Wf_n, const float* __restrict__ bs_n,
    const u16* __restrict__ hnf_p, u16* __restrict__ hnf_c,
    u16* __restrict__ hist1, float* __restrict__ c_n)
{
    const int tid = threadIdx.x;
    const int l = tid & 63, l15 = l & 15;
    const size_t lo8 = (size_t)l * 8;

    if ((int)blockIdx.x < nlstm) {
        // ----------------- temporal+spatial LSTM tile -----------------
        const bool spatial = blockIdx.x < 528;
        int rb, jc;
        if (spatial) {
            int orig = (blockIdx.x & 7) * 66 + (blockIdx.x >> 3);
            rb = orig >> 3; jc = orig & 7;
        } else {
            int q = blockIdx.x - 528;
            rb = q >> 3; jc = q & 7;
        }
        const u16* Ef = spatial ? sef_step : tef_step;
        const u16* Hf = spatial ? hsf_p : htf_p;
        const u16* Wf = spatial ? Wf_s : Wf_t;
        const float* bs = spatial ? bs_s : bs_t;
        u16* Hfc = spatial ? hsf_c : htf_c;
        u16* Hd  = spatial ? hs_d : ht_d;
        float* C  = spatial ? c_s : c_t;

        const int wid = tid >> 6;
        const int wm = wid >> 1, wn = wid & 1;
        const int rb16 = rb * 8 + wm * 4;
        const int jb16 = jc * 8 + wn * 4;

        f32x4 acc[4][4];
        #pragma unroll
        for (int g = 0; g < 4; ++g) {
            float bv = bs[jc * 128 + wn * 64 + g * 16 + l15];
            #pragma unroll
            for (int mf = 0; mf < 4; ++mf) acc[mf][g] = (f32x4){bv, bv, bv, bv};
        }

        auto loadA = [&](int kc, bf16x8* a) {
            #pragma unroll
            for (int mf = 0; mf < 4; ++mf) {
                const u16* p = (kc < 4)
                    ? Ef + (((size_t)(rb16 + mf)) * 4 + kc) * 512 + lo8
                    : Hf + (((size_t)(rb16 + mf)) * 8 + (kc - 4)) * 512 + lo8;
                a[mf] = *(const bf16x8*)p;
            }
        };
        auto loadB = [&](int kc, bf16x8* b) {
            #pragma unroll
            for (int g = 0; g < 4; ++g)
                b[g] = *(const bf16x8*)(Wf + (((size_t)(jb16 + g)) * 12 + kc) * 512 + lo8);
        };
        auto domfma = [&](bf16x8* a, bf16x8* b) {
            #pragma unroll
            for (int mf = 0; mf < 4; ++mf)
                #pragma unroll
                for (int g = 0; g < 4; ++g)
                    acc[mf][g] = __builtin_amdgcn_mfma_f32_16x16x32_bf16(a[mf], b[g], acc[mf][g], 0, 0, 0);
        };

        bf16x8 a0[4], b0[4], a1[4], b1[4];
        loadA(0, a0); loadB(0, b0);
        #pragma unroll
        for (int kc = 0; kc < 12; kc += 2) {
            loadA(kc + 1, a1); loadB(kc + 1, b1);
            domfma(a0, b0);
            if (kc + 2 < 12) { loadA(kc + 2, a0); loadB(kc + 2, b0); }
            domfma(a1, b1);
        }

        const int cell = (jc * 2 + wn) * 16 + l15;
        const int rofs = (l >> 4) << 2;
        const int cpart = (cell >> 5) * 512 + ((cell >> 3) & 3) * 128 + (cell & 7);
        #pragma unroll
        for (int mf = 0; mf < 4; ++mf) {
            int r16 = rb16 + mf;
            #pragma unroll
            for (int r = 0; r < 4; ++r) {
                int rlow = rofs + r;
                size_t doff = ((size_t)r16 * 16 + rlow) * 256 + cell;
                float gi = acc[mf][0][r], gf = acc[mf][1][r], gg = acc[mf][2][r], go = acc[mf][3][r];
                float c2 = sigm(gf) * C[doff] + sigm(gi) * ftanh(gg);
                float h2 = sigm(go) * ftanh(c2);
                C[doff] = c2;
                u16 hb = f2bf(h2);
                Hd[doff] = hb;
                Hfc[(size_t)r16 * 4096 + cpart + rlow * 8] = hb;
            }
        }
        return;
    }

    // ----------------- node LSTM tile (step t_node) -----------------
    if (t_node < 0) return;
    const int nb = blockIdx.x - nlstm;          // 0..191
    const int rb16 = nb >> 2, jq = nb & 3;
    const int wn = tid >> 6;                    // 4 waves split 256 cols

    f32x4 acc[4];
    #pragma unroll
    for (int g = 0; g < 4; ++g) {
        float bv = bs_n[jq * 256 + wn * 64 + g * 16 + l15];
        acc[g] = (f32x4){bv, bv, bv, bv};
    }
    #pragma unroll
    for (int kc = 0; kc < 16; ++kc) {
        const u16* p;
        if (kc < 4)       p = ninf_t + ((size_t)rb16 * 4 + kc) * 512 + lo8;
        else if (kc < 8)  p = einf   + ((size_t)rb16 * 4 + (kc - 4)) * 512 + lo8;
        else              p = hnf_p  + ((size_t)rb16 * 8 + (kc - 8)) * 512 + lo8;
        bf16x8 af = *(const bf16x8*)p;
        #pragma unroll
        for (int g = 0; g < 4; ++g) {
            bf16x8 bf = *(const bf16x8*)(Wf_n + (((size_t)(jq * 16 + wn * 4 + g)) * 16 + kc) * 512 + lo8);
            acc[g] = __builtin_amdgcn_mfma_f32_16x16x32_bf16(af, bf, acc[g], 0, 0, 0);
        }
    }
    const int cell = (jq * 4 + wn) * 16 + l15;
    const int rofs = (l >> 4) << 2;
    const int cpart = (cell >> 5) * 512 + ((cell >> 3) & 3) * 128 + (cell & 7);
    #pragma unroll
    for (int r = 0; r < 4; ++r) {
        int rlow = rofs + r;
        size_t doff = ((size_t)rb16 * 16 + rlow) * 256 + cell;
        float gi = acc[0][r], gf = acc[1][r], gg = acc[2][r], go = acc[3][r];
        float c2 = sigm(gf) * c_n[doff] + sigm(gi) * ftanh(gg);
        float h2 = sigm(go) * ftanh(c2);
        c_n[doff] = c2;
        u16 hb = f2bf(h2);
        hist1[doff] = hb;
        hnf_c[(size_t)rb16 * 4096 + cpart + rlow * 8] = hb;
    }
}

// ---------------------------------------------------------------------------
// D1: attention + edge-input, 48 blocks x 16 rows, MFMA-based.
// ---------------------------------------------------------------------------
__global__ __launch_bounds__(256) void attn_kernel(
    const u16* __restrict__ htf, const u16* __restrict__ hs_d,
    const u16* __restrict__ Wqf, const float* __restrict__ bq,
    const u16* __restrict__ Wkqf, const float* __restrict__ bk,
    const u16* __restrict__ Wef, const float* __restrict__ b_edge,
    u16* __restrict__ einf)
{
    const int rb16 = blockIdx.x;
    const int r0 = rb16 * 16;
    const int tid = threadIdx.x, l = tid & 63, wid = tid >> 6, l15 = l & 15;
    const size_t lo8 = (size_t)l * 8;

    __shared__ float q_lds[16][68];
    __shared__ float qk_lds[16][260];
    __shared__ float sc_lds[16][12];
    __shared__ float w_lds[16][12];
    __shared__ float ha_lds[16][260];
    __shared__ float qb_lds[16];

    if (wid == 0) {   // q = h_t @ Wq^T : 4 jb x 8 kc
        f32x4 qa[4];
        #pragma unroll
        for (int jb = 0; jb < 4; ++jb) qa[jb] = (f32x4){0.f, 0.f, 0.f, 0.f};
        #pragma unroll
        for (int kc = 0; kc < 8; ++kc) {
            bf16x8 af = *(const bf16x8*)(htf + ((size_t)rb16 * 8 + kc) * 512 + lo8);
            #pragma unroll
            for (int jb = 0; jb < 4; ++jb) {
                bf16x8 bf = *(const bf16x8*)(Wqf + ((size_t)(jb * 8 + kc)) * 512 + lo8);
                qa[jb] = __builtin_amdgcn_mfma_f32_16x16x32_bf16(af, bf, qa[jb], 0, 0, 0);
            }
        }
        #pragma unroll
        for (int jb = 0; jb < 4; ++jb) {
            int a = jb * 16 + l15;
            #pragma unroll
            for (int r = 0; r < 4; ++r)
                q_lds[(l >> 4) * 4 + r][a] = qa[jb][r] + bq[a];
        }
    }
    __syncthreads();
    if (wid == 0) {   // qk = q @ Wk : 16 jb x 2 kc (K = 64)
        f32x4 ka[16];
        #pragma unroll
        for (int jb = 0; jb < 16; ++jb) ka[jb] = (f32x4){0.f, 0.f, 0.f, 0.f};
        #pragma unroll
        for (int kc = 0; kc < 2; ++kc) {
            int a0 = kc * 32 + (l >> 4) * 8;
            bf16x8 af;
            #pragma unroll
            for (int e = 0; e < 8; ++e)
                ((u16*)&af)[e] = f2bf(q_lds[l15][a0 + e]);
            #pragma unroll
            for (int jb = 0; jb < 16; ++jb) {
                bf16x8 bf = *(const bf16x8*)(Wkqf + ((size_t)(jb * 2 + kc)) * 512 + lo8);
                ka[jb] = __builtin_amdgcn_mfma_f32_16x16x32_bf16(af, bf, ka[jb], 0, 0, 0);
            }
        }
        #pragma unroll
        for (int jb = 0; jb < 16; ++jb)
            #pragma unroll
            for (int r = 0; r < 4; ++r)
                qk_lds[(l >> 4) * 4 + r][jb * 16 + l15] = ka[jb][r];
    }
    if (wid == 1 && l < 16) {   // qb[row] = q_full . bk
        float s = 0.f;
        for (int a = 0; a < 64; ++a) s = fmaf(q_lds[l][a], bk[a], s);
        qb_lds[l] = s;
    }
    __syncthreads();
    if (tid < 176) {   // scores: (row, kk)
        int row = tid / 11, kk = tid - row * 11;
        int r = r0 + row;
        int srow = (r / 12) * 132 + (r % 12) * 11 + kk;
        const u16* hp = hs_d + (size_t)srow * 256;
        float s = 0.f;
        for (int k = 0; k < 256; k += 8) {
            u16x8 v = *(const u16x8*)(hp + k);
            #pragma unroll
            for (int e = 0; e < 8; ++e) s = fmaf(qk_lds[row][k + e], bf2f(v[e]), s);
        }
        sc_lds[row][kk] = (s + qb_lds[row]) * TEMP_;
    }
    __syncthreads();
    if (tid < 16) {   // softmax over 11
        float m = sc_lds[tid][0];
        #pragma unroll
        for (int kk = 1; kk < 11; ++kk) m = fmaxf(m, sc_lds[tid][kk]);
        float ssum = 0.f;
        float wv[11];
        #pragma unroll
        for (int kk = 0; kk < 11; ++kk) { wv[kk] = __expf(sc_lds[tid][kk] - m); ssum += wv[kk]; }
        float inv = 1.f / ssum;
        #pragma unroll
        for (int kk = 0; kk < 11; ++kk) w_lds[tid][kk] = wv[kk] * inv;
    }
    __syncthreads();
    {   // h_attn: thread = (row, 16-col chunk)
        int row = tid >> 4, c0 = (tid & 15) * 16;
        int r = r0 + row;
        int sbase = (r / 12) * 132 + (r % 12) * 11;
        float acc[16];
        #pragma unroll
        for (int e = 0; e < 16; ++e) acc[e] = 0.f;
        #pragma unroll
        for (int kk = 0; kk < 11; ++kk) {
            float wv = w_lds[row][kk];
            const u16* hp = hs_d + (size_t)(sbase + kk) * 256 + c0;
            u16x8 v0 = *(const u16x8*)hp;
            u16x8 v1 = *(const u16x8*)(hp + 8);
            #pragma unroll
            for (int e = 0; e < 8; ++e) {
                acc[e]     = fmaf(wv, bf2f(v0[e]), acc[e]);
                acc[8 + e] = fmaf(wv, bf2f(v1[e]), acc[8 + e]);
            }
        }
        #pragma unroll
        for (int e = 0; e < 16; ++e) ha_lds[row][c0 + e] = acc[e];
    }
    __syncthreads();
    {   // ein = [h_t | h_attn] @ W_edge^T : wave handles 2 jb16, 16 kc
        f32x4 ea[2];
        ea[0] = (f32x4){0.f, 0.f, 0.f, 0.f};
        ea[1] = (f32x4){0.f, 0.f, 0.f, 0.f};
        #pragma unroll
        for (int kc = 0; kc < 16; ++kc) {
            bf16x8 af;
            if (kc < 8) {
                af = *(const bf16x8*)(htf + ((size_t)rb16 * 8 + kc) * 512 + lo8);
            } else {
                int k0 = (kc - 8) * 32 + (l >> 4) * 8;
                #pragma unroll
                for (int e = 0; e < 8; ++e)
                    ((u16*)&af)[e] = f2bf(ha_lds[l15][k0 + e]);
            }
            #pragma unroll
            for (int j2 = 0; j2 < 2; ++j2) {
                bf16x8 bf = *(const bf16x8*)(Wef + ((size_t)((wid * 2 + j2) * 16 + kc)) * 512 + lo8);
                ea[j2] = __builtin_amdgcn_mfma_f32_16x16x32_bf16(af, bf, ea[j2], 0, 0, 0);
            }
        }
        #pragma unroll
        for (int j2 = 0; j2 < 2; ++j2) {
            int cell = (wid * 2 + j2) * 16 + l15;
            #pragma unroll
            for (int r = 0; r < 4; ++r) {
                int row = (l >> 4) * 4 + r;
                float v = ea[j2][r] + b_edge[cell];
                v = v > 0.f ? v : 0.f;
                einf[((size_t)rb16 * 4 + (cell >> 5)) * 512
                     + (((cell >> 3) & 3) * 16 + row) * 8 + (cell & 7)] = f2bf(v);
            }
        }
    }
}

// out[b,t,n,q] = hist[t+1] . W_out^T + b_out
__global__ __launch_bounds__(256) void out_kernel(
    const u16* __restrict__ hist1, const float* __restrict__ W_out,
    const float* __restrict__ b_out, float* __restrict__ out)
{
    const int lane = threadIdx.x & 63;
    const int grp = threadIdx.x >> 6;
    for (int ridx = blockIdx.x * 4 + grp; ridx < 32 * 768; ridx += gridDim.x * 4) {
        int t = ridx / 768, row = ridx % 768;
        int b = row / 12, n = row % 12;
        const u16* h = &hist1[(size_t)ridx * 256];
        float hv[4];
        #pragma unroll
        for (int i = 0; i < 4; ++i) hv[i] = bf2f(h[i * 64 + lane]);
        #pragma unroll
        for (int q = 0; q < 5; ++q) {
            float s = 0.f;
            #pragma unroll
            for (int i = 0; i < 4; ++i) s = fmaf(hv[i], W_out[q * 256 + i * 64 + lane], s);
            #pragma unroll
            for (int off = 32; off > 0; off >>= 1) s += __shfl_down(s, off, 64);
            if (lane == 0)
                out[(((size_t)b * T_ + t) * N_ + n) * 5 + q] = s + b_out[q];
        }
    }
}

extern "C" void kernel_launch(void* const* d_in, const int* in_sizes, int n_in,
                              void* d_out, int out_size, void* d_ws, size_t ws_size,
                              hipStream_t stream)
{
    const float* nodes = (const float*)d_in[0];
    const float* et    = (const float*)d_in[1];
    const float* es    = (const float*)d_in[2];
    const float* W_te = (const float*)d_in[3];  const float* b_te = (const float*)d_in[4];
    const float* te_Wih = (const float*)d_in[5]; const float* te_Whh = (const float*)d_in[6];
    const float* te_bih = (const float*)d_in[7]; const float* te_bhh = (const float*)d_in[8];
    const float* W_se = (const float*)d_in[9];  const float* b_se = (const float*)d_in[10];
    const float* se_Wih = (const float*)d_in[11]; const float* se_Whh = (const float*)d_in[12];
    const float* se_bih = (const float*)d_in[13]; const float* se_bhh = (const float*)d_in[14];
    const float* Wq = (const float*)d_in[15]; const float* bq = (const float*)d_in[16];
    const float* Wk = (const float*)d_in[17]; const float* bk = (const float*)d_in[18];
    const float* W_node = (const float*)d_in[19]; const float* b_node = (const float*)d_in[20];
    const float* W_edge = (const float*)d_in[21]; const float* b_edge = (const float*)d_in[22];
    const float* nr_Wih = (const float*)d_in[23]; const float* nr_Whh = (const float*)d_in[24];
    const float* nr_bih = (const float*)d_in[25]; const float* nr_bhh = (const float*)d_in[26];
    const float* W_out = (const float*)d_in[27]; const float* b_out = (const float*)d_in[28];

    char* base = (char*)d_ws;
    size_t off = 0;
    auto A = [&](size_t bytes) { char* p = base + off; off += (bytes + 255) & ~(size_t)255; return p; };

    // zero region: c-states (f32) + t=0 frag h-states (bf16), contiguous
    float* c_t = (float*)A(768 * 256 * 4);
    float* c_s = (float*)A((size_t)8448 * 256 * 4);
    float* c_n = (float*)A(768 * 256 * 4);
    u16* htf0 = (u16*)A(768 * 256 * 2);
    u16* hsf0 = (u16*)A((size_t)8448 * 256 * 2);
    u16* hnf0 = (u16*)A(768 * 256 * 2);
    size_t zero_bytes = off;
    u16* htf1 = (u16*)A(768 * 256 * 2);
    u16* hsf1 = (u16*)A((size_t)8448 * 256 * 2);
    u16* hnf1 = (u16*)A(768 * 256 * 2);
    u16* ht_d = (u16*)A(768 * 256 * 2);
    u16* hs_d = (u16*)A((size_t)8448 * 256 * 2);
    u16* hist = (u16*)A((size_t)33 * 768 * 256 * 2);
    u16* einf = (u16*)A(768 * 128 * 2);
    u16* tef  = (u16*)A((size_t)32 * 768 * 128 * 2);
    u16* ninf = (u16*)A((size_t)32 * 768 * 128 * 2);
    u16* Wf_t = (u16*)A(1024 * 384 * 2);
    u16* Wf_s = (u16*)A(1024 * 384 * 2);
    u16* Wf_n = (u16*)A(1024 * 512 * 2);
    float* bs_t = (float*)A(1024 * 4);
    float* bs_s = (float*)A(1024 * 4);
    float* bs_n = (float*)A(1024 * 4);
    u16* Wqf  = (u16*)A(2048 * 8 * 2);
    u16* Wkqf = (u16*)A(2048 * 8 * 2);
    u16* Wef  = (u16*)A(8192 * 8 * 2);

    const size_t sef_full_bytes = (size_t)32 * 8448 * 128 * 2;
    bool sef_full = (off + sef_full_bytes + 4096) <= ws_size;
    u16* sef = (u16*)A(sef_full ? sef_full_bytes : (size_t)8448 * 128 * 2);

    hipMemsetAsync(base, 0, zero_bytes, stream);

    prep_kernel<<<256, 256, 0, stream>>>(
        te_Wih, te_Whh, te_bih, te_bhh, se_Wih, se_Whh, se_bih, se_bhh,
        nr_Wih, nr_Whh, nr_bih, nr_bhh, Wq, Wk, W_edge,
        Wf_t, Wf_s, Wf_n, bs_t, bs_s, bs_n, Wqf, Wkqf, Wef);

    emb_tn_kernel<<<1536, 256, 0, stream>>>(et, nodes, W_te, b_te, W_node, b_node, tef, ninf);

    if (sef_full)
        emb_se_kernel<<<16896, 256, 0, stream>>>(0, es, W_se, b_se, sef);
    else
        emb_se_kernel<<<528, 256, 0, stream>>>(0, es, W_se, b_se, sef);

    u16* htf[2] = {htf0, htf1};
    u16* hsf[2] = {hsf0, hsf1};
    u16* hnf[2] = {hnf0, hnf1};

    auto sef_ptr = [&](int t) {
        return sef_full ? sef + (size_t)t * 528 * 4 * 512 : sef;
    };

    // lstm(0), no node
    lstm_node_kernel<<<576, 256, 0, stream>>>(
        576, -1,
        sef_ptr(0), tef, Wf_t, bs_t, Wf_s, bs_s,
        htf[0], htf[1], ht_d, c_t, hsf[0], hsf[1], hs_d, c_s,
        ninf, einf, Wf_n, bs_n, hnf[0], hnf[1], hist, c_n);

    for (int t = 0; t < T_; ++t) {
        int cc = (t & 1) ^ 1;              // lstm(t) wrote htf[cc]/hsf[cc]
        attn_kernel<<<48, 256, 0, stream>>>(
            htf[cc], hs_d, Wqf, bq, Wkqf, bk, Wef, b_edge, einf);

        int npp = t & 1, ncc = npp ^ 1;    // node(t): hnf[npp] -> hnf[ncc]
        if (t < T_ - 1) {
            if (!sef_full)
                emb_se_kernel<<<528, 256, 0, stream>>>(t + 1, es, W_se, b_se, sef);
            int pp2 = (t + 1) & 1, cc2 = pp2 ^ 1;   // lstm(t+1)
            lstm_node_kernel<<<768, 256, 0, stream>>>(
                576, t,
                sef_ptr(t + 1), tef + (size_t)(t + 1) * 48 * 4 * 512,
                Wf_t, bs_t, Wf_s, bs_s,
                htf[pp2], htf[cc2], ht_d, c_t, hsf[pp2], hsf[cc2], hs_d, c_s,
                ninf + (size_t)t * 48 * 4 * 512, einf, Wf_n, bs_n,
                hnf[npp], hnf[ncc], hist + (size_t)(t + 1) * 768 * 256, c_n);
        } else {
            lstm_node_kernel<<<192, 256, 0, stream>>>(
                0, t,
                sef_ptr(0), tef, Wf_t, bs_t, Wf_s, bs_s,
                htf[0], htf[1], ht_d, c_t, hsf[0], hsf[1], hs_d, c_s,
                ninf + (size_t)t * 48 * 4 * 512, einf, Wf_n, bs_n,
                hnf[npp], hnf[ncc], hist + (size_t)(t + 1) * 768 * 256, c_n);
        }
    }

    out_kernel<<<1536, 256, 0, stream>>>(hist + (size_t)768 * 256, W_out, b_out, (float*)d_out);
}

// Round 5
// 1572.164 us; speedup vs baseline: 4.1875x; 1.0003x over previous
//
#include <hip/hip_runtime.h>
#include <math.h>

#define B_ 64
#define T_ 32
#define N_ 12
#define NS_ 132
#define KN_ 11
#define TEMP_ 1.375f   // K_NEIGH / sqrt(ATTN) = 11/8

typedef unsigned short u16;
typedef __attribute__((ext_vector_type(8))) short bf16x8;
typedef __attribute__((ext_vector_type(8))) unsigned short u16x8;
typedef __attribute__((ext_vector_type(4))) float f32x4;

__device__ __forceinline__ float sigm(float x) { return 1.f / (1.f + __expf(-x)); }
__device__ __forceinline__ float ftanh(float x) {
    float a = fabsf(x);
    float e = __expf(-2.f * a);
    float t = (1.f - e) / (1.f + e);
    return copysignf(t, x);
}
__device__ __forceinline__ u16 f2bf(float x) {
    union { float f; unsigned u; } v; v.f = x;
    unsigned r = v.u + 0x7fffu + ((v.u >> 16) & 1u);
    return (u16)(r >> 16);
}
__device__ __forceinline__ float bf2f(u16 h) {
    union { unsigned u; float f; } v; v.u = ((unsigned)h) << 16; return v.f;
}
// reordered gate-space col j -> original gate col: j = cellhi*64 + gate*16 + celllo
__device__ __forceinline__ int origcol(int j) {
    return ((j >> 4) & 3) * 256 + ((j >> 6) << 4) + (j & 15);
}

// Fragment layout for M[R][K] (A/B operand of mfma 16x16x32 bf16):
//   tile = (r>>4)*(K/32) + (k>>5); lane = ((k>>3)&3)*16 + (r&15); elem = k&7
//   flat u16 index = tile*512 + lane*8 + elem

// ---------------------------------------------------------------------------
// prep: all weights -> bf16 fragment layout, fused biases.
// ---------------------------------------------------------------------------
__global__ __launch_bounds__(256) void prep_kernel(
    const float* __restrict__ te_Wih, const float* __restrict__ te_Whh,
    const float* __restrict__ te_bih, const float* __restrict__ te_bhh,
    const float* __restrict__ se_Wih, const float* __restrict__ se_Whh,
    const float* __restrict__ se_bih, const float* __restrict__ se_bhh,
    const float* __restrict__ nr_Wih, const float* __restrict__ nr_Whh,
    const float* __restrict__ nr_bih, const float* __restrict__ nr_bhh,
    const float* __restrict__ Wq, const float* __restrict__ Wk,
    const float* __restrict__ W_edge,
    u16* __restrict__ Wf_t, u16* __restrict__ Wf_s, u16* __restrict__ Wf_n,
    float* __restrict__ bs_t, float* __restrict__ bs_s, float* __restrict__ bs_n,
    u16* __restrict__ Wqf, u16* __restrict__ Wkqf, u16* __restrict__ Wef)
{
    int idx = blockIdx.x * 256 + threadIdx.x;
    if (idx < 49152) {                 // Wf_t / Wf_s: 64 jb16 x 12 kc x 64 lanes
        int l = idx & 63, kc = (idx >> 6) % 12, jb16 = idx / 768;
        int j = jb16 * 16 + (l & 15);
        int c = origcol(j);
        int k0 = kc * 32 + (l >> 4) * 8;
        u16x8 vt, vs;
        #pragma unroll
        for (int i = 0; i < 8; ++i) {
            int k = k0 + i;
            vt[i] = f2bf((k < 128) ? te_Wih[c * 128 + k] : te_Whh[c * 256 + (k - 128)]);
            vs[i] = f2bf((k < 128) ? se_Wih[c * 128 + k] : se_Whh[c * 256 + (k - 128)]);
        }
        *(u16x8*)(Wf_t + (size_t)idx * 8) = vt;
        *(u16x8*)(Wf_s + (size_t)idx * 8) = vs;
    }
    if (idx < 65536) {                 // Wf_n: 64 jb16 x 16 kc x 64 lanes
        int l = idx & 63, kc = (idx >> 6) & 15, jb16 = idx >> 10;
        int j = jb16 * 16 + (l & 15);
        int c = origcol(j);
        int k0 = kc * 32 + (l >> 4) * 8;
        u16x8 vn;
        #pragma unroll
        for (int i = 0; i < 8; ++i) {
            int k = k0 + i;
            vn[i] = f2bf((k < 256) ? nr_Wih[c * 256 + k] : nr_Whh[c * 256 + (k - 256)]);
        }
        *(u16x8*)(Wf_n + (size_t)idx * 8) = vn;
    }
    if (idx < 1024) {
        int c = origcol(idx);
        bs_t[idx] = te_bih[c] + te_bhh[c];
        bs_s[idx] = se_bih[c] + se_bhh[c];
        bs_n[idx] = nr_bih[c] + nr_bhh[c];
    }
    if (idx < 2048) {                  // Wqf: B[a][k], a<64, K=256 -> 4 jb x 8 kc
        int l = idx & 63, tile = idx >> 6;
        int a = (tile >> 3) * 16 + (l & 15);
        int k0 = (tile & 7) * 32 + (l >> 4) * 8;
        u16x8 v;
        #pragma unroll
        for (int i = 0; i < 8; ++i) v[i] = f2bf(Wq[a * 256 + k0 + i]);
        *(u16x8*)(Wqf + (size_t)idx * 8) = v;
    }
    if (idx < 2048) {                  // Wkqf: B[j][a] = Wk[a][j], j<256, K=64 -> 16 jb x 2 kc
        int l = idx & 63, tile = idx >> 6;
        int j = (tile >> 1) * 16 + (l & 15);
        int a0 = (tile & 1) * 32 + (l >> 4) * 8;
        u16x8 v;
        #pragma unroll
        for (int i = 0; i < 8; ++i) v[i] = f2bf(Wk[(a0 + i) * 256 + j]);
        *(u16x8*)(Wkqf + (size_t)idx * 8) = v;
    }
    if (idx < 8192) {                  // Wef: B[c][k], c<128, K=512 -> 8 jb x 16 kc
        int l = idx & 63, tile = idx >> 6;
        int c = (tile >> 4) * 16 + (l & 15);
        int k0 = (tile & 15) * 32 + (l >> 4) * 8;
        u16x8 v;
        #pragma unroll
        for (int i = 0; i < 8; ++i) v[i] = f2bf(W_edge[c * 512 + k0 + i]);
        *(u16x8*)(Wef + (size_t)idx * 8) = v;
    }
}

// te/nin embeddings in fragment layout: u = ((t*48+rb16)*4+kc)*64 + l
__global__ __launch_bounds__(256) void emb_tn_kernel(
    const float* __restrict__ et, const float* __restrict__ nodes,
    const float* __restrict__ W_te, const float* __restrict__ b_te,
    const float* __restrict__ W_node, const float* __restrict__ b_node,
    u16* __restrict__ tef, u16* __restrict__ ninf)
{
    int u = blockIdx.x * 256 + threadIdx.x;   // 32*48*4*64 = 393216 exact
    int l = u & 63, kc = (u >> 6) & 3;
    int rt = u >> 8;
    int rb16 = rt % 48, t = rt / 48;
    int row = rb16 * 16 + (l & 15);
    int b = row / 12, n = row - b * 12;
    size_t src = (((size_t)b * T_ + t) * N_ + n) * 2;
    float e0 = et[src], e1 = et[src + 1];
    float n0 = nodes[src], n1 = nodes[src + 1];
    int k0 = kc * 32 + (l >> 4) * 8;
    u16x8 vt, vn;
    #pragma unroll
    for (int i = 0; i < 8; ++i) {
        int k = k0 + i;
        float x = fmaf(e0, W_te[k * 2], fmaf(e1, W_te[k * 2 + 1], b_te[k]));
        vt[i] = f2bf(fmaxf(x, 0.f));
        float y = fmaf(n0, W_node[k * 2], fmaf(n1, W_node[k * 2 + 1], b_node[k]));
        vn[i] = f2bf(fmaxf(y, 0.f));
    }
    *(u16x8*)(tef + (size_t)u * 8) = vt;
    *(u16x8*)(ninf + (size_t)u * 8) = vn;
}

// spatial embeddings, fragment layout: u = ((trel*528+rb16)*4+kc)*64 + l
__global__ __launch_bounds__(256) void emb_se_kernel(
    int t0, const float* __restrict__ es,
    const float* __restrict__ W_se, const float* __restrict__ b_se,
    u16* __restrict__ sef)
{
    int u = blockIdx.x * 256 + threadIdx.x;
    int l = u & 63, kc = (u >> 6) & 3;
    int rt = u >> 8;
    int rb16 = rt % 528, trel = rt / 528;
    int row = rb16 * 16 + (l & 15);
    int b = row / NS_, s = row - b * NS_;
    size_t src = (((size_t)b * T_ + (t0 + trel)) * NS_ + s) * 2;
    float e0 = es[src], e1 = es[src + 1];
    int k0 = kc * 32 + (l >> 4) * 8;
    u16x8 v;
    #pragma unroll
    for (int i = 0; i < 8; ++i) {
        int k = k0 + i;
        float x = fmaf(e0, W_se[k * 2], fmaf(e1, W_se[k * 2 + 1], b_se[k]));
        v[i] = f2bf(fmaxf(x, 0.f));
    }
    *(u16x8*)(sef + (size_t)u * 8) = v;
}

// ---------------------------------------------------------------------------
// D2: blocks [0, nlstm) = temporal+spatial LSTM step t ; blocks [nlstm, +192)
// = node LSTM step t_node (runs concurrently; disjoint buffers).
// ---------------------------------------------------------------------------
__global__ __launch_bounds__(256) void lstm_node_kernel(
    int nlstm, int t_node,
    const u16* __restrict__ sef_step, const u16* __restrict__ tef_step,
    const u16* __restrict__ Wf_t, const float* __restrict__ bs_t,
    const u16* __restrict__ Wf_s, const float* __restrict__ bs_s,
    const u16* __restrict__ htf_p, u16* __restrict__ htf_c, u16* __restrict__ ht_d,
    float* __restrict__ c_t,
    const u16* __restrict__ hsf_p, u16* __restrict__ hsf_c, u16* __restrict__ hs_d,
    float* __restrict__ c_s,
    const u16* __restrict__ ninf_t, const u16* __restrict__ einf,
    const u16* __restrict__ Wf_n, const float* __restrict__ bs_n,
    const u16* __restrict__ hnf_p, u16* __restrict__ hnf_c,
    u16* __restrict__ hist1, float* __restrict__ c_n)
{
    const int tid = threadIdx.x;
    const int l = tid & 63, l15 = l & 15;
    const size_t lo8 = (size_t)l * 8;

    if ((int)blockIdx.x < nlstm) {
        // ----------------- temporal+spatial LSTM tile -----------------
        const bool spatial = blockIdx.x < 528;
        int rb, jc;
        if (spatial) {
            int orig = (blockIdx.x & 7) * 66 + (blockIdx.x >> 3);
            rb = orig >> 3; jc = orig & 7;
        } else {
            int q = blockIdx.x - 528;
            rb = q >> 3; jc = q & 7;
        }
        const u16* Ef = spatial ? sef_step : tef_step;
        const u16* Hf = spatial ? hsf_p : htf_p;
        const u16* Wf = spatial ? Wf_s : Wf_t;
        const float* bs = spatial ? bs_s : bs_t;
        u16* Hfc = spatial ? hsf_c : htf_c;
        u16* Hd  = spatial ? hs_d : ht_d;
        float* C  = spatial ? c_s : c_t;

        const int wid = tid >> 6;
        const int wm = wid >> 1, wn = wid & 1;
        const int rb16 = rb * 8 + wm * 4;
        const int jb16 = jc * 8 + wn * 4;

        f32x4 acc[4][4];
        #pragma unroll
        for (int g = 0; g < 4; ++g) {
            float bv = bs[jc * 128 + wn * 64 + g * 16 + l15];
            #pragma unroll
            for (int mf = 0; mf < 4; ++mf) acc[mf][g] = (f32x4){bv, bv, bv, bv};
        }

        auto loadA = [&](int kc, bf16x8* a) {
            #pragma unroll
            for (int mf = 0; mf < 4; ++mf) {
                const u16* p = (kc < 4)
                    ? Ef + (((size_t)(rb16 + mf)) * 4 + kc) * 512 + lo8
                    : Hf + (((size_t)(rb16 + mf)) * 8 + (kc - 4)) * 512 + lo8;
                a[mf] = *(const bf16x8*)p;
            }
        };
        auto loadB = [&](int kc, bf16x8* b) {
            #pragma unroll
            for (int g = 0; g < 4; ++g)
                b[g] = *(const bf16x8*)(Wf + (((size_t)(jb16 + g)) * 12 + kc) * 512 + lo8);
        };
        auto domfma = [&](bf16x8* a, bf16x8* b) {
            #pragma unroll
            for (int mf = 0; mf < 4; ++mf)
                #pragma unroll
                for (int g = 0; g < 4; ++g)
                    acc[mf][g] = __builtin_amdgcn_mfma_f32_16x16x32_bf16(a[mf], b[g], acc[mf][g], 0, 0, 0);
        };

        bf16x8 a0[4], b0[4], a1[4], b1[4];
        loadA(0, a0); loadB(0, b0);
        #pragma unroll
        for (int kc = 0; kc < 12; kc += 2) {
            loadA(kc + 1, a1); loadB(kc + 1, b1);
            domfma(a0, b0);
            if (kc + 2 < 12) { loadA(kc + 2, a0); loadB(kc + 2, b0); }
            domfma(a1, b1);
        }

        const int cell = (jc * 2 + wn) * 16 + l15;
        const int rofs = (l >> 4) << 2;
        const int cpart = (cell >> 5) * 512 + ((cell >> 3) & 3) * 128 + (cell & 7);
        #pragma unroll
        for (int mf = 0; mf < 4; ++mf) {
            int r16 = rb16 + mf;
            #pragma unroll
            for (int r = 0; r < 4; ++r) {
                int rlow = rofs + r;
                size_t doff = ((size_t)r16 * 16 + rlow) * 256 + cell;
                float gi = acc[mf][0][r], gf = acc[mf][1][r], gg = acc[mf][2][r], go = acc[mf][3][r];
                float c2 = sigm(gf) * C[doff] + sigm(gi) * ftanh(gg);
                float h2 = sigm(go) * ftanh(c2);
                C[doff] = c2;
                u16 hb = f2bf(h2);
                Hd[doff] = hb;
                Hfc[(size_t)r16 * 4096 + cpart + rlow * 8] = hb;
            }
        }
        return;
    }

    // ----------------- node LSTM tile (step t_node) -----------------
    if (t_node < 0) return;
    const int nb = blockIdx.x - nlstm;          // 0..191
    const int rb16 = nb >> 2, jq = nb & 3;
    const int wn = tid >> 6;                    // 4 waves split 256 cols

    f32x4 acc[4];
    #pragma unroll
    for (int g = 0; g < 4; ++g) {
        float bv = bs_n[jq * 256 + wn * 64 + g * 16 + l15];
        acc[g] = (f32x4){bv, bv, bv, bv};
    }
    #pragma unroll
    for (int kc = 0; kc < 16; ++kc) {
        const u16* p;
        if (kc < 4)       p = ninf_t + ((size_t)rb16 * 4 + kc) * 512 + lo8;
        else if (kc < 8)  p = einf   + ((size_t)rb16 * 4 + (kc - 4)) * 512 + lo8;
        else              p = hnf_p  + ((size_t)rb16 * 8 + (kc - 8)) * 512 + lo8;
        bf16x8 af = *(const bf16x8*)p;
        #pragma unroll
        for (int g = 0; g < 4; ++g) {
            bf16x8 bf = *(const bf16x8*)(Wf_n + (((size_t)(jq * 16 + wn * 4 + g)) * 16 + kc) * 512 + lo8);
            acc[g] = __builtin_amdgcn_mfma_f32_16x16x32_bf16(af, bf, acc[g], 0, 0, 0);
        }
    }
    const int cell = (jq * 4 + wn) * 16 + l15;
    const int rofs = (l >> 4) << 2;
    const int cpart = (cell >> 5) * 512 + ((cell >> 3) & 3) * 128 + (cell & 7);
    #pragma unroll
    for (int r = 0; r < 4; ++r) {
        int rlow = rofs + r;
        size_t doff = ((size_t)rb16 * 16 + rlow) * 256 + cell;
        float gi = acc[0][r], gf = acc[1][r], gg = acc[2][r], go = acc[3][r];
        float c2 = sigm(gf) * c_n[doff] + sigm(gi) * ftanh(gg);
        float h2 = sigm(go) * ftanh(c2);
        c_n[doff] = c2;
        u16 hb = f2bf(h2);
        hist1[doff] = hb;
        hnf_c[(size_t)rb16 * 4096 + cpart + rlow * 8] = hb;
    }
}

// ---------------------------------------------------------------------------
// D1: attention + edge-input, 48 blocks x 16 rows, MFMA-based.
// ---------------------------------------------------------------------------
__global__ __launch_bounds__(256) void attn_kernel(
    const u16* __restrict__ htf, const u16* __restrict__ hs_d,
    const u16* __restrict__ Wqf, const float* __restrict__ bq,
    const u16* __restrict__ Wkqf, const float* __restrict__ bk,
    const u16* __restrict__ Wef, const float* __restrict__ b_edge,
    u16* __restrict__ einf)
{
    const int rb16 = blockIdx.x;
    const int r0 = rb16 * 16;
    const int tid = threadIdx.x, l = tid & 63, wid = tid >> 6, l15 = l & 15;
    const size_t lo8 = (size_t)l * 8;

    __shared__ float q_lds[16][68];
    __shared__ float qk_lds[16][260];
    __shared__ float sc_lds[16][12];
    __shared__ float w_lds[16][12];
    __shared__ float ha_lds[16][260];
    __shared__ float qb_lds[16];

    if (wid == 0) {   // q = h_t @ Wq^T : 4 jb x 8 kc
        f32x4 qa[4];
        #pragma unroll
        for (int jb = 0; jb < 4; ++jb) qa[jb] = (f32x4){0.f, 0.f, 0.f, 0.f};
        #pragma unroll
        for (int kc = 0; kc < 8; ++kc) {
            bf16x8 af = *(const bf16x8*)(htf + ((size_t)rb16 * 8 + kc) * 512 + lo8);
            #pragma unroll
            for (int jb = 0; jb < 4; ++jb) {
                bf16x8 bf = *(const bf16x8*)(Wqf + ((size_t)(jb * 8 + kc)) * 512 + lo8);
                qa[jb] = __builtin_amdgcn_mfma_f32_16x16x32_bf16(af, bf, qa[jb], 0, 0, 0);
            }
        }
        #pragma unroll
        for (int jb = 0; jb < 4; ++jb) {
            int a = jb * 16 + l15;
            #pragma unroll
            for (int r = 0; r < 4; ++r)
                q_lds[(l >> 4) * 4 + r][a] = qa[jb][r] + bq[a];
        }
    }
    __syncthreads();
    if (wid == 0) {   // qk = q @ Wk : 16 jb x 2 kc (K = 64)
        f32x4 ka[16];
        #pragma unroll
        for (int jb = 0; jb < 16; ++jb) ka[jb] = (f32x4){0.f, 0.f, 0.f, 0.f};
        #pragma unroll
        for (int kc = 0; kc < 2; ++kc) {
            int a0 = kc * 32 + (l >> 4) * 8;
            bf16x8 af;
            #pragma unroll
            for (int e = 0; e < 8; ++e)
                ((u16*)&af)[e] = f2bf(q_lds[l15][a0 + e]);
            #pragma unroll
            for (int jb = 0; jb < 16; ++jb) {
                bf16x8 bf = *(const bf16x8*)(Wkqf + ((size_t)(jb * 2 + kc)) * 512 + lo8);
                ka[jb] = __builtin_amdgcn_mfma_f32_16x16x32_bf16(af, bf, ka[jb], 0, 0, 0);
            }
        }
        #pragma unroll
        for (int jb = 0; jb < 16; ++jb)
            #pragma unroll
            for (int r = 0; r < 4; ++r)
                qk_lds[(l >> 4) * 4 + r][jb * 16 + l15] = ka[jb][r];
    }
    if (wid == 1 && l < 16) {   // qb[row] = q_full . bk
        float s = 0.f;
        for (int a = 0; a < 64; ++a) s = fmaf(q_lds[l][a], bk[a], s);
        qb_lds[l] = s;
    }
    __syncthreads();
    if (tid < 176) {   // scores: (row, kk)
        int row = tid / 11, kk = tid - row * 11;
        int r = r0 + row;
        int srow = (r / 12) * 132 + (r % 12) * 11 + kk;
        const u16* hp = hs_d + (size_t)srow * 256;
        float s = 0.f;
        for (int k = 0; k < 256; k += 8) {
            u16x8 v = *(const u16x8*)(hp + k);
            #pragma unroll
            for (int e = 0; e < 8; ++e) s = fmaf(qk_lds[row][k + e], bf2f(v[e]), s);
        }
        sc_lds[row][kk] = (s + qb_lds[row]) * TEMP_;
    }
    __syncthreads();
    if (tid < 16) {   // softmax over 11
        float m = sc_lds[tid][0];
        #pragma unroll
        for (int kk = 1; kk < 11; ++kk) m = fmaxf(m, sc_lds[tid][kk]);
        float ssum = 0.f;
        float wv[11];
        #pragma unroll
        for (int kk = 0; kk < 11; ++kk) { wv[kk] = __expf(sc_lds[tid][kk] - m); ssum += wv[kk]; }
        float inv = 1.f / ssum;
        #pragma unroll
        for (int kk = 0; kk < 11; ++kk) w_lds[tid][kk] = wv[kk] * inv;
    }
    __syncthreads();
    {   // h_attn: thread = (row, 16-col chunk)
        int row = tid >> 4, c0 = (tid & 15) * 16;
        int r = r0 + row;
        int sbase = (r / 12) * 132 + (r % 12) * 11;
        float acc[16];
        #pragma unroll
        for (int e = 0; e < 16; ++e) acc[e] = 0.f;
        #pragma unroll
        for (int kk = 0; kk < 11; ++kk) {
            float wv = w_lds[row][kk];
            const u16* hp = hs_d + (size_t)(sbase + kk) * 256 + c0;
            u16x8 v0 = *(const u16x8*)hp;
            u16x8 v1 = *(const u16x8*)(hp + 8);
            #pragma unroll
            for (int e = 0; e < 8; ++e) {
                acc[e]     = fmaf(wv, bf2f(v0[e]), acc[e]);
                acc[8 + e] = fmaf(wv, bf2f(v1[e]), acc[8 + e]);
            }
        }
        #pragma unroll
        for (int e = 0; e < 16; ++e) ha_lds[row][c0 + e] = acc[e];
    }
    __syncthreads();
    {   // ein = [h_t | h_attn] @ W_edge^T : wave handles 2 jb16, 16 kc
        f32x4 ea[2];
        ea[0] = (f32x4){0.f, 0.f, 0.f, 0.f};
        ea[1] = (f32x4){0.f, 0.f, 0.f, 0.f};
        #pragma unroll
        for (int kc = 0; kc < 16; ++kc) {
            bf16x8 af;
            if (kc < 8) {
                af = *(const bf16x8*)(htf + ((size_t)rb16 * 8 + kc) * 512 + lo8);
            } else {
                int k0 = (kc - 8) * 32 + (l >> 4) * 8;
                #pragma unroll
                for (int e = 0; e < 8; ++e)
                    ((u16*)&af)[e] = f2bf(ha_lds[l15][k0 + e]);
            }
            #pragma unroll
            for (int j2 = 0; j2 < 2; ++j2) {
                bf16x8 bf = *(const bf16x8*)(Wef + ((size_t)((wid * 2 + j2) * 16 + kc)) * 512 + lo8);
                ea[j2] = __builtin_amdgcn_mfma_f32_16x16x32_bf16(af, bf, ea[j2], 0, 0, 0);
            }
        }
        #pragma unroll
        for (int j2 = 0; j2 < 2; ++j2) {
            int cell = (wid * 2 + j2) * 16 + l15;
            #pragma unroll
            for (int r = 0; r < 4; ++r) {
                int row = (l >> 4) * 4 + r;
                float v = ea[j2][r] + b_edge[cell];
                v = v > 0.f ? v : 0.f;
                einf[((size_t)rb16 * 4 + (cell >> 5)) * 512
                     + (((cell >> 3) & 3) * 16 + row) * 8 + (cell & 7)] = f2bf(v);
            }
        }
    }
}

// out[b,t,n,q] = hist[t+1] . W_out^T + b_out
__global__ __launch_bounds__(256) void out_kernel(
    const u16* __restrict__ hist1, const float* __restrict__ W_out,
    const float* __restrict__ b_out, float* __restrict__ out)
{
    const int lane = threadIdx.x & 63;
    const int grp = threadIdx.x >> 6;
    for (int ridx = blockIdx.x * 4 + grp; ridx < 32 * 768; ridx += gridDim.x * 4) {
        int t = ridx / 768, row = ridx % 768;
        int b = row / 12, n = row % 12;
        const u16* h = &hist1[(size_t)ridx * 256];
        float hv[4];
        #pragma unroll
        for (int i = 0; i < 4; ++i) hv[i] = bf2f(h[i * 64 + lane]);
        #pragma unroll
        for (int q = 0; q < 5; ++q) {
            float s = 0.f;
            #pragma unroll
            for (int i = 0; i < 4; ++i) s = fmaf(hv[i], W_out[q * 256 + i * 64 + lane], s);
            #pragma unroll
            for (int off = 32; off > 0; off >>= 1) s += __shfl_down(s, off, 64);
            if (lane == 0)
                out[(((size_t)b * T_ + t) * N_ + n) * 5 + q] = s + b_out[q];
        }
    }
}

extern "C" void kernel_launch(void* const* d_in, const int* in_sizes, int n_in,
                              void* d_out, int out_size, void* d_ws, size_t ws_size,
                              hipStream_t stream)
{
    const float* nodes = (const float*)d_in[0];
    const float* et    = (const float*)d_in[1];
    const float* es    = (const float*)d_in[2];
    const float* W_te = (const float*)d_in[3];  const float* b_te = (const float*)d_in[4];
    const float* te_Wih = (const float*)d_in[5]; const float* te_Whh = (const float*)d_in[6];
    const float* te_bih = (const float*)d_in[7]; const float* te_bhh = (const float*)d_in[8];
    const float* W_se = (const float*)d_in[9];  const float* b_se = (const float*)d_in[10];
    const float* se_Wih = (const float*)d_in[11]; const float* se_Whh = (const float*)d_in[12];
    const float* se_bih = (const float*)d_in[13]; const float* se_bhh = (const float*)d_in[14];
    const float* Wq = (const float*)d_in[15]; const float* bq = (const float*)d_in[16];
    const float* Wk = (const float*)d_in[17]; const float* bk = (const float*)d_in[18];
    const float* W_node = (const float*)d_in[19]; const float* b_node = (const float*)d_in[20];
    const float* W_edge = (const float*)d_in[21]; const float* b_edge = (const float*)d_in[22];
    const float* nr_Wih = (const float*)d_in[23]; const float* nr_Whh = (const float*)d_in[24];
    const float* nr_bih = (const float*)d_in[25]; const float* nr_bhh = (const float*)d_in[26];
    const float* W_out = (const float*)d_in[27]; const float* b_out = (const float*)d_in[28];

    char* base = (char*)d_ws;
    size_t off = 0;
    auto A = [&](size_t bytes) { char* p = base + off; off += (bytes + 255) & ~(size_t)255; return p; };

    // zero region: c-states (f32) + t=0 frag h-states (bf16), contiguous
    float* c_t = (float*)A(768 * 256 * 4);
    float* c_s = (float*)A((size_t)8448 * 256 * 4);
    float* c_n = (float*)A(768 * 256 * 4);
    u16* htf0 = (u16*)A(768 * 256 * 2);
    u16* hsf0 = (u16*)A((size_t)8448 * 256 * 2);
    u16* hnf0 = (u16*)A(768 * 256 * 2);
    size_t zero_bytes = off;
    u16* htf1 = (u16*)A(768 * 256 * 2);
    u16* hsf1 = (u16*)A((size_t)8448 * 256 * 2);
    u16* hnf1 = (u16*)A(768 * 256 * 2);
    u16* ht_d = (u16*)A(768 * 256 * 2);
    u16* hs_d = (u16*)A((size_t)8448 * 256 * 2);
    u16* hist = (u16*)A((size_t)33 * 768 * 256 * 2);
    u16* einf = (u16*)A(768 * 128 * 2);
    u16* tef  = (u16*)A((size_t)32 * 768 * 128 * 2);
    u16* ninf = (u16*)A((size_t)32 * 768 * 128 * 2);
    u16* Wf_t = (u16*)A(1024 * 384 * 2);
    u16* Wf_s = (u16*)A(1024 * 384 * 2);
    u16* Wf_n = (u16*)A(1024 * 512 * 2);
    float* bs_t = (float*)A(1024 * 4);
    float* bs_s = (float*)A(1024 * 4);
    float* bs_n = (float*)A(1024 * 4);
    u16* Wqf  = (u16*)A(2048 * 8 * 2);
    u16* Wkqf = (u16*)A(2048 * 8 * 2);
    u16* Wef  = (u16*)A(8192 * 8 * 2);

    const size_t sef_full_bytes = (size_t)32 * 8448 * 128 * 2;
    bool sef_full = (off + sef_full_bytes + 4096) <= ws_size;
    u16* sef = (u16*)A(sef_full ? sef_full_bytes : (size_t)8448 * 128 * 2);

    hipMemsetAsync(base, 0, zero_bytes, stream);

    prep_kernel<<<256, 256, 0, stream>>>(
        te_Wih, te_Whh, te_bih, te_bhh, se_Wih, se_Whh, se_bih, se_bhh,
        nr_Wih, nr_Whh, nr_bih, nr_bhh, Wq, Wk, W_edge,
        Wf_t, Wf_s, Wf_n, bs_t, bs_s, bs_n, Wqf, Wkqf, Wef);

    emb_tn_kernel<<<1536, 256, 0, stream>>>(et, nodes, W_te, b_te, W_node, b_node, tef, ninf);

    if (sef_full)
        emb_se_kernel<<<16896, 256, 0, stream>>>(0, es, W_se, b_se, sef);
    else
        emb_se_kernel<<<528, 256, 0, stream>>>(0, es, W_se, b_se, sef);

    u16* htf[2] = {htf0, htf1};
    u16* hsf[2] = {hsf0, hsf1};
    u16* hnf[2] = {hnf0, hnf1};

    auto sef_ptr = [&](int t) {
        return sef_full ? sef + (size_t)t * 528 * 4 * 512 : sef;
    };

    // lstm(0), no node
    lstm_node_kernel<<<576, 256, 0, stream>>>(
        576, -1,
        sef_ptr(0), tef, Wf_t, bs_t, Wf_s, bs_s,
        htf[0], htf[1], ht_d, c_t, hsf[0], hsf[1], hs_d, c_s,
        ninf, einf, Wf_n, bs_n, hnf[0], hnf[1], hist, c_n);

    for (int t = 0; t < T_; ++t) {
        int cc = (t & 1) ^ 1;              // lstm(t) wrote htf[cc]/hsf[cc]
        attn_kernel<<<48, 256, 0, stream>>>(
            htf[cc], hs_d, Wqf, bq, Wkqf, bk, Wef, b_edge, einf);

        int npp = t & 1, ncc = npp ^ 1;    // node(t): hnf[npp] -> hnf[ncc]
        if (t < T_ - 1) {
            if (!sef_full)
                emb_se_kernel<<<528, 256, 0, stream>>>(t + 1, es, W_se, b_se, sef);
            int pp2 = (t + 1) & 1, cc2 = pp2 ^ 1;   // lstm(t+1)
            lstm_node_kernel<<<768, 256, 0, stream>>>(
                576, t,
                sef_ptr(t + 1), tef + (size_t)(t + 1) * 48 * 4 * 512,
                Wf_t, bs_t, Wf_s, bs_s,
                htf[pp2], htf[cc2], ht_d, c_t, hsf[pp2], hsf[cc2], hs_d, c_s,
                ninf + (size_t)t * 48 * 4 * 512, einf, Wf_n, bs_n,
                hnf[npp], hnf[ncc], hist + (size_t)(t + 1) * 768 * 256, c_n);
        } else {
            lstm_node_kernel<<<192, 256, 0, stream>>>(
                0, t,
                sef_ptr(0), tef, Wf_t, bs_t, Wf_s, bs_s,
                htf[0], htf[1], ht_d, c_t, hsf[0], hsf[1], hs_d, c_s,
                ninf + (size_t)t * 48 * 4 * 512, einf, Wf_n, bs_n,
                hnf[npp], hnf[ncc], hist + (size_t)(t + 1) * 768 * 256, c_n);
        }
    }

    out_kernel<<<1536, 256, 0, stream>>>(hist + (size_t)768 * 256, W_out, b_out, (float*)d_out);
}